// Round 9
// baseline (609.842 us; speedup 1.0000x reference)
//
#include <hip/hip_runtime.h>

#define N_NODES   50000
#define N_EDGES   800000
#define HID       64
#define NUM_GRAPHS 50
#define EPS       1e-5f
#define NB_COMBINE 256
#define NHPAD     50176          // 98 * 512, padded histogram/scan size
#define SCAN_B    98

typedef __attribute__((ext_vector_type(8))) short short8;
typedef __attribute__((ext_vector_type(4))) float f32x4;

__device__ __forceinline__ unsigned short bfbits(float x) {
    __bf16 h = (__bf16)x;
    return __builtin_bit_cast(unsigned short, h);
}
__device__ __forceinline__ float bffloat(unsigned short b) {
    return __builtin_bit_cast(float, (unsigned int)b << 16);
}
// 8 fp32 -> bf16 hi/lo fragments
__device__ __forceinline__ void cvt8(const float4& a, const float4& b,
                                     short8& hi, short8& lo) {
    float f[8] = {a.x, a.y, a.z, a.w, b.x, b.y, b.z, b.w};
#pragma unroll
    for (int i = 0; i < 8; ++i) {
        unsigned short hb = bfbits(f[i]);
        hi[i] = (short)hb;
        lo[i] = (short)bfbits(f[i] - bffloat(hb));
    }
}

// ---------------------------------------------------------------------------
// Int histogram of dst (degree count).
__global__ __launch_bounds__(256) void k_hist(const int* __restrict__ dst,
                                              int* __restrict__ ihist) {
    int tid = blockIdx.x * blockDim.x + threadIdx.x;
    int stride = gridDim.x * blockDim.x;
    for (int e = tid; e < N_EDGES; e += stride) atomicAdd(&ihist[dst[e]], 1);
}

// Exclusive scan, pass 1: per-block (512 elems) local scan + block sums.
__global__ __launch_bounds__(512) void k_scan1(const int* __restrict__ ihist,
                                               int* __restrict__ off,
                                               int* __restrict__ bsum) {
    __shared__ int s[512];
    const int t = threadIdx.x, i = blockIdx.x * 512 + t;
    const int v = ihist[i];
    s[t] = v;
    __syncthreads();
    for (int o = 1; o < 512; o <<= 1) {
        int u = (t >= o) ? s[t - o] : 0;
        __syncthreads();
        s[t] += u;
        __syncthreads();
    }
    off[i] = s[t] - v;
    if (t == 511) bsum[blockIdx.x] = s[t];
}

// pass 2: serial exclusive scan of the 98 block sums.
__global__ void k_scan2(const int* __restrict__ bsum, int* __restrict__ bscan) {
    if (threadIdx.x == 0) {
        int acc = 0;
        for (int b = 0; b < SCAN_B; ++b) { bscan[b] = acc; acc += bsum[b]; }
    }
}

// pass 3: add block offsets; duplicate into mutable cursor for the scatter.
__global__ __launch_bounds__(512) void k_scan3(int* __restrict__ off,
                                               const int* __restrict__ bscan,
                                               int* __restrict__ off_cur) {
    const int i = blockIdx.x * 512 + threadIdx.x;
    const int v = off[i] + bscan[i >> 9];
    off[i] = v;
    off_cur[i] = v;
}

// Counting-sort scatter: ssrc in dst order; pinv[e] = sorted position.
__global__ __launch_bounds__(256) void k_scatter(const int* __restrict__ src,
                                                 const int* __restrict__ dst,
                                                 int* __restrict__ off_cur,
                                                 int* __restrict__ ssrc,
                                                 int* __restrict__ pinv) {
    int tid = blockIdx.x * blockDim.x + threadIdx.x;
    int stride = gridDim.x * blockDim.x;
    for (int e = tid; e < N_EDGES; e += stride) {
        const int d = dst[e];
        const int p = atomicAdd(&off_cur[d], 1);
        ssrc[p] = src[e];
        pinv[e] = p;
    }
}

// ---------------------------------------------------------------------------
// ea[E][32] fp32 -> bf16 hi/lo interleaved [E][64] in dst-sorted edge order.
// One full 128B line per edge (no partial-line scatter). 4 lanes per edge.
__global__ __launch_bounds__(256) void k_prepEA(const float* __restrict__ ea,
                                                const int* __restrict__ pinv,
                                                unsigned short* __restrict__ eaP) {
    int t = blockIdx.x * blockDim.x + threadIdx.x;
    if (t >= N_EDGES * 4) return;
    const int e = t >> 2, q = t & 3;
    const int p = pinv[e];
    float4 a = *(const float4*)(ea + (size_t)e * 32 + q * 8);
    float4 b = *(const float4*)(ea + (size_t)e * 32 + q * 8 + 4);
    short8 hi, lo;
    cvt8(a, b, hi, lo);
    *(short8*)(eaP + (size_t)p * 64 + q * 8) = hi;
    *(short8*)(eaP + (size_t)p * 64 + 32 + q * 8) = lo;
}

// ---------------------------------------------------------------------------
__global__ void k_gcnt(const int* __restrict__ batch, float* __restrict__ gcnt) {
    int g = threadIdx.x;
    if (g >= NUM_GRAPHS) return;
    auto lb = [&](int val) {
        int lo = 0, hi = N_NODES;
        while (lo < hi) { int mid = (lo + hi) >> 1; if (batch[mid] < val) lo = mid + 1; else hi = mid; }
        return lo;
    };
    gcnt[g] = (float)(lb(g + 1) - lb(g));
}

// ---------------------------------------------------------------------------
// Weight prep: W[96][64] fp32 -> Wt hi/lo [64][104] bf16 (transposed, padded).
__global__ void k_prepW(const float* __restrict__ W, unsigned short* __restrict__ Whi,
                        unsigned short* __restrict__ Wlo) {
    int t = blockIdx.x * blockDim.x + threadIdx.x;
    if (t >= 96 * 64) return;
    int k = t >> 6, n = t & 63;
    float x = W[t];
    unsigned short hb = bfbits(x);
    float lof = x - bffloat(hb);
    Whi[n * 104 + k] = hb;
    Wlo[n * 104 + k] = bfbits(lof);
}

// ---------------------------------------------------------------------------
// x[N,64] fp32 -> packed bf16 hi/lo arrays (same row-major layout).
__global__ __launch_bounds__(256) void k_prepX(const float* __restrict__ x,
                                               unsigned short* __restrict__ xhi,
                                               unsigned short* __restrict__ xlo) {
    int t = blockIdx.x * blockDim.x + threadIdx.x;
    if (t >= N_NODES * 8) return;
    const float* r = x + (size_t)t * 8;
    float4 a = ((const float4*)r)[0];
    float4 b = ((const float4*)r)[1];
    short8 hi, lo;
    cvt8(a, b, hi, lo);
    *(short8*)(xhi + (size_t)t * 8) = hi;
    *(short8*)(xlo + (size_t)t * 8) = lo;
}

// ---------------------------------------------------------------------------
// Fused BN-apply (layer1) + layer-2 operand prep.
__global__ __launch_bounds__(256) void k_prepH(const float* __restrict__ h,
                                               const float* __restrict__ ss,
                                               float* __restrict__ hn,
                                               unsigned short* __restrict__ hhi,
                                               unsigned short* __restrict__ hlo) {
    int t = blockIdx.x * blockDim.x + threadIdx.x;
    if (t >= N_NODES * 8) return;
    const int f0 = (t & 7) * 8;
    float4 sca = *(const float4*)(ss + f0);
    float4 scb = *(const float4*)(ss + f0 + 4);
    float4 sha = *(const float4*)(ss + 64 + f0);
    float4 shb = *(const float4*)(ss + 64 + f0 + 4);
    const float* r = h + (size_t)t * 8;
    float4 a = ((const float4*)r)[0];
    float4 b = ((const float4*)r)[1];
    a.x = fmaxf(a.x * sca.x + sha.x, 0.f);
    a.y = fmaxf(a.y * sca.y + sha.y, 0.f);
    a.z = fmaxf(a.z * sca.z + sha.z, 0.f);
    a.w = fmaxf(a.w * sca.w + sha.w, 0.f);
    b.x = fmaxf(b.x * scb.x + shb.x, 0.f);
    b.y = fmaxf(b.y * scb.y + shb.y, 0.f);
    b.z = fmaxf(b.z * scb.z + shb.z, 0.f);
    b.w = fmaxf(b.w * scb.w + shb.w, 0.f);
    ((float4*)(hn + (size_t)t * 8))[0] = a;
    ((float4*)(hn + (size_t)t * 8))[1] = b;
    short8 hi, lo;
    cvt8(a, b, hi, lo);
    *(short8*)(hhi + (size_t)t * 8) = hi;
    *(short8*)(hlo + (size_t)t * 8) = lo;
}

// ---------------------------------------------------------------------------
// Node-centric edge-message + mean-aggregation. One wave per dst node (CSR):
// loop ceil(deg/16) MFMA tiles over the node's contiguous sorted edges,
// masked ReLU-reduce each tile in registers, accumulate, one plain store of
// the mean row. NO atomics, NO LDS, no segment logic.
__global__ __launch_bounds__(256) void k_edge(const unsigned short* __restrict__ xhi,
                                              const unsigned short* __restrict__ xlo,
                                              const unsigned short* __restrict__ eaP,
                                              const int*   __restrict__ ssrc,
                                              const int*   __restrict__ csr,
                                              const unsigned short* __restrict__ Whi,
                                              const unsigned short* __restrict__ Wlo,
                                              const float* __restrict__ bias,
                                              float* __restrict__ aggr) {
    const int tid  = threadIdx.x;
    const int lane = tid & 63;
    const int w    = tid >> 6;
    const int n    = blockIdx.x * 4 + w;   // node id; grid covers exactly N_NODES

    const int fr   = lane & 15;
    const int hi4  = lane >> 4;
    const int koff = hi4 * 8;
    const int rb   = hi4 * 4;

    const int beg = csr[n];
    const int end = csr[n + 1];

    float bv0 = bias[fr], bv1 = bias[16 + fr], bv2 = bias[32 + fr], bv3 = bias[48 + fr];

    float vtot = 0.f;
    for (int t0 = beg; t0 < end; t0 += 16) {
        const int rem = end - t0;                    // > 0, wave-uniform
        const int row = t0 + min(fr, rem - 1);       // clamped per-lane edge row
        const int s = ssrc[row];

        short8 ah0 = *(const short8*)(xhi + (size_t)s * 64 + koff);
        short8 ah1 = *(const short8*)(xhi + (size_t)s * 64 + 32 + koff);
        short8 al0 = *(const short8*)(xlo + (size_t)s * 64 + koff);
        short8 al1 = *(const short8*)(xlo + (size_t)s * 64 + 32 + koff);
        short8 ah2 = *(const short8*)(eaP + (size_t)row * 64 + koff);
        short8 al2 = *(const short8*)(eaP + (size_t)row * 64 + 32 + koff);

        f32x4 acc[4] = {f32x4{bv0, bv0, bv0, bv0}, f32x4{bv1, bv1, bv1, bv1},
                        f32x4{bv2, bv2, bv2, bv2}, f32x4{bv3, bv3, bv3, bv3}};
#pragma unroll
        for (int kb = 0; kb < 3; ++kb) {
            const short8 a  = (kb == 0) ? ah0 : (kb == 1) ? ah1 : ah2;
            const short8 al = (kb == 0) ? al0 : (kb == 1) ? al1 : al2;
#pragma unroll
            for (int nn = 0; nn < 4; ++nn) {
                const short8 bh = *(const short8*)(Whi + (nn * 16 + fr) * 104 + kb * 32 + koff);
                const short8 bl = *(const short8*)(Wlo + (nn * 16 + fr) * 104 + kb * 32 + koff);
                acc[nn] = __builtin_amdgcn_mfma_f32_16x16x32_bf16(a,  bh, acc[nn], 0, 0, 0);
                acc[nn] = __builtin_amdgcn_mfma_f32_16x16x32_bf16(al, bh, acc[nn], 0, 0, 0);
                acc[nn] = __builtin_amdgcn_mfma_f32_16x16x32_bf16(a,  bl, acc[nn], 0, 0, 0);
            }
        }

        // masked ReLU column-sum over valid rows (C layout: col=nn*16+fr, row=rb+j)
        float v0 = 0.f, v1 = 0.f, v2 = 0.f, v3 = 0.f;
#pragma unroll
        for (int j = 0; j < 4; ++j) {
            const bool in = (rb + j) < rem;
            v0 += in ? fmaxf(acc[0][j], 0.f) : 0.f;
            v1 += in ? fmaxf(acc[1][j], 0.f) : 0.f;
            v2 += in ? fmaxf(acc[2][j], 0.f) : 0.f;
            v3 += in ? fmaxf(acc[3][j], 0.f) : 0.f;
        }
        v0 += __shfl_xor(v0, 16); v0 += __shfl_xor(v0, 32);
        v1 += __shfl_xor(v1, 16); v1 += __shfl_xor(v1, 32);
        v2 += __shfl_xor(v2, 16); v2 += __shfl_xor(v2, 32);
        v3 += __shfl_xor(v3, 16); v3 += __shfl_xor(v3, 32);
        vtot += hi4 == 0 ? v0 : hi4 == 1 ? v1 : hi4 == 2 ? v2 : v3;
    }

    const int deg = end - beg;
    const float inv = deg > 0 ? 1.0f / (float)deg : 0.f;
    aggr[(size_t)n * 64 + lane] = vtot * inv;   // mean; full coverage -> no memset
}

// ---------------------------------------------------------------------------
// h = xin @ Wr + aggr (aggr already mean); per-block BN partial sums.
__global__ __launch_bounds__(256) void k_combine(const float* __restrict__ xin,
                                                 const float* __restrict__ Wr,
                                                 const float* __restrict__ aggr,
                                                 float* __restrict__ h,
                                                 float* __restrict__ partial) {
    const int lane = threadIdx.x & 63;
    const int wv   = threadIdx.x >> 6;
    const int wid  = (blockIdx.x * blockDim.x + threadIdx.x) >> 6;
    const int nw   = (gridDim.x * blockDim.x) >> 6;

    float w[64];
#pragma unroll
    for (int k = 0; k < 64; ++k) w[k] = Wr[k * 64 + lane];

    float rs = 0.f, rq = 0.f;
    for (int n = wid; n < N_NODES; n += nw) {
        const float* __restrict__ xr = xin + (size_t)n * 64;
        float acc = aggr[(size_t)n * 64 + lane];
#pragma unroll
        for (int k = 0; k < 64; ++k) acc += xr[k] * w[k];
        h[(size_t)n * 64 + lane] = acc;
        rs += acc;
        rq += acc * acc;
    }
    __shared__ float ssum[4][64];
    __shared__ float ssq[4][64];
    ssum[wv][lane] = rs;
    ssq[wv][lane]  = rq;
    __syncthreads();
    if (threadIdx.x < 64) {
        float s = ssum[0][lane] + ssum[1][lane] + ssum[2][lane] + ssum[3][lane];
        partial[blockIdx.x * 128 + lane] = s;
    } else if (threadIdx.x < 128) {
        int l = threadIdx.x - 64;
        float q = ssq[0][l] + ssq[1][l] + ssq[2][l] + ssq[3][l];
        partial[blockIdx.x * 128 + 64 + l] = q;
    }
}

// ---------------------------------------------------------------------------
__global__ void k_bnfin(const float* __restrict__ partial, const float* __restrict__ g,
                        const float* __restrict__ be, float* __restrict__ ss) {
    __shared__ float tot[128];
    int t = threadIdx.x;
    float s = 0.f;
    for (int b = 0; b < NB_COMBINE; ++b) s += partial[b * 128 + t];
    tot[t] = s;
    __syncthreads();
    if (t < 64) {
        float mu  = tot[t] * (1.0f / (float)N_NODES);
        float var = tot[64 + t] * (1.0f / (float)N_NODES) - mu * mu;
        float sc  = g[t] * rsqrtf(var + EPS);
        ss[t]      = sc;
        ss[64 + t] = be[t] - mu * sc;
    }
}

// ---------------------------------------------------------------------------
// Fused BN-apply (layer2) + global mean pool partial sums (sorted-run atomics).
__global__ __launch_bounds__(256) void k_bnpool(const float* __restrict__ h,
                                                const float* __restrict__ ss,
                                                const int* __restrict__ batch,
                                                float* __restrict__ gsum) {
    const int lane = threadIdx.x & 63;
    const int wid  = (blockIdx.x * blockDim.x + threadIdx.x) >> 6;
    const int nw   = (gridDim.x * blockDim.x) >> 6;
    const float sc = ss[lane];
    const float sh = ss[64 + lane];
    const int chunk = (N_NODES + nw - 1) / nw;
    const int n0 = wid * chunk;
    const int n1 = min(n0 + chunk, N_NODES);
    int curg = -1;
    float acc = 0.f;
    for (int n = n0; n < n1; ++n) {
        int g = __builtin_amdgcn_readfirstlane(batch[n]);
        if (g != curg) {
            if (curg >= 0) unsafeAtomicAdd(&gsum[curg * 64 + lane], acc);
            curg = g;
            acc = 0.f;
        }
        acc += fmaxf(h[(size_t)n * 64 + lane] * sc + sh, 0.f);
    }
    if (curg >= 0) unsafeAtomicAdd(&gsum[curg * 64 + lane], acc);
}

// ---------------------------------------------------------------------------
__global__ void k_final(const float* __restrict__ gsum, const float* __restrict__ gcnt,
                        const float* __restrict__ Wro, const float* __restrict__ bro,
                        float* __restrict__ out) {
    int g = blockIdx.x;
    int lane = threadIdx.x;
    float v = gsum[g * 64 + lane] / fmaxf(gcnt[g], 1.0f) * Wro[lane];
#pragma unroll
    for (int off = 32; off > 0; off >>= 1) v += __shfl_down(v, off, 64);
    if (lane == 0) out[g] = v + bro[0];
}

// ---------------------------------------------------------------------------
extern "C" void kernel_launch(void* const* d_in, const int* in_sizes, int n_in,
                              void* d_out, int out_size, void* d_ws, size_t ws_size,
                              hipStream_t stream) {
    (void)in_sizes; (void)n_in; (void)out_size; (void)ws_size;
    const float* x    = (const float*)d_in[0];
    const int*   ei   = (const int*)d_in[1];   // [2, E]
    const float* ea   = (const float*)d_in[2];
    const int*   batch= (const int*)d_in[3];
    const float* Wn1  = (const float*)d_in[4];
    const float* bn1  = (const float*)d_in[5];
    const float* Wr1  = (const float*)d_in[6];
    const float* g1   = (const float*)d_in[7];
    const float* be1  = (const float*)d_in[8];
    const float* Wn2  = (const float*)d_in[9];
    const float* bn2  = (const float*)d_in[10];
    const float* Wr2  = (const float*)d_in[11];
    const float* g2   = (const float*)d_in[12];
    const float* be2  = (const float*)d_in[13];
    const float* Wro  = (const float*)d_in[14];
    const float* bro  = (const float*)d_in[15];
    const int* src = ei;
    const int* dst = ei + N_EDGES;

    float* ws = (float*)d_ws;
    // ---- zeroed region: [gsum | ihist] (aggr no longer needs zeroing) ----
    float* gsum   = ws;                               // 3200
    int*   ihist  = (int*)(gsum + 3200);              // NHPAD
    const size_t zero_floats = 3200 + NHPAD;
    // ---- non-zeroed ----
    float* aggr   = (float*)(ihist + NHPAD);          // N*64
    float* h      = aggr + (size_t)N_NODES * 64;
    float* hn     = h + (size_t)N_NODES * 64;
    float* gcnt   = hn + (size_t)N_NODES * 64;        // 64
    float* part1  = gcnt + 64;                        // NB*128
    float* part2  = part1 + NB_COMBINE * 128;
    float* ss1    = part2 + NB_COMBINE * 128;         // 128
    float* ss2    = ss1 + 128;                        // 128
    unsigned short* wb = (unsigned short*)(ss2 + 128);
    unsigned short* Wh1 = wb;                         // 64*104 each
    unsigned short* Wl1 = wb + 6656;
    unsigned short* Wh2 = wb + 13312;
    unsigned short* Wl2 = wb + 19968;
    int* off     = (int*)(wb + 26624);                // NHPAD (CSR pointers, preserved)
    int* off_cur = off + NHPAD;                       // NHPAD
    int* bsum    = off_cur + NHPAD;                   // 128
    int* bscan   = bsum + 128;                        // 128
    int* ssrc    = bscan + 128;                       // E
    int* pinv    = ssrc + N_EDGES;                    // E
    unsigned short* xhi = (unsigned short*)(pinv + N_EDGES); // N*64 each
    unsigned short* xlo = xhi + (size_t)N_NODES * 64;
    unsigned short* hhi = xlo + (size_t)N_NODES * 64;
    unsigned short* hlo = hhi + (size_t)N_NODES * 64;
    unsigned short* eaP = hlo + (size_t)N_NODES * 64;    // E*64

    hipMemsetAsync(d_ws, 0, zero_floats * sizeof(float), stream);

    // ---- edge sort by dst (shared by both layers) ----
    k_hist<<<512, 256, 0, stream>>>(dst, ihist);
    k_scan1<<<SCAN_B, 512, 0, stream>>>(ihist, off, bsum);
    k_scan2<<<1, 64, 0, stream>>>(bsum, bscan);
    k_scan3<<<SCAN_B, 512, 0, stream>>>(off, bscan, off_cur);
    k_scatter<<<512, 256, 0, stream>>>(src, dst, off_cur, ssrc, pinv);
    k_prepEA<<<N_EDGES * 4 / 256, 256, 0, stream>>>(ea, pinv, eaP);

    k_gcnt<<<1, 64, 0, stream>>>(batch, gcnt);
    k_prepW<<<24, 256, 0, stream>>>(Wn1, Wh1, Wl1);
    k_prepW<<<24, 256, 0, stream>>>(Wn2, Wh2, Wl2);
    k_prepX<<<(N_NODES * 8 + 255) / 256, 256, 0, stream>>>(x, xhi, xlo);

    // ---- layer 1 ----
    k_edge<<<N_NODES / 4, 256, 0, stream>>>(xhi, xlo, eaP, ssrc, off, Wh1, Wl1, bn1, aggr);
    k_combine<<<NB_COMBINE, 256, 0, stream>>>(x, Wr1, aggr, h, part1);
    k_bnfin<<<1, 128, 0, stream>>>(part1, g1, be1, ss1);
    k_prepH<<<(N_NODES * 8 + 255) / 256, 256, 0, stream>>>(h, ss1, hn, hhi, hlo);

    // ---- layer 2 ----
    k_edge<<<N_NODES / 4, 256, 0, stream>>>(hhi, hlo, eaP, ssrc, off, Wh2, Wl2, bn2, aggr);
    k_combine<<<NB_COMBINE, 256, 0, stream>>>(hn, Wr2, aggr, h, part2);
    k_bnfin<<<1, 128, 0, stream>>>(part2, g2, be2, ss2);

    // ---- readout (BN-apply fused into pool) ----
    k_bnpool<<<256, 256, 0, stream>>>(h, ss2, batch, gsum);
    k_final<<<NUM_GRAPHS, 64, 0, stream>>>(gsum, gcnt, Wro, bro, (float*)d_out);
}

// Round 10
// 482.331 us; speedup vs baseline: 1.2644x; 1.2644x over previous
//
#include <hip/hip_runtime.h>

#define N_NODES   50000
#define N_EDGES   800000
#define HID       64
#define NUM_GRAPHS 50
#define EPS       1e-5f
#define NB_COMBINE 256
#define NHPAD     50176          // 98 * 512, padded histogram/scan size
#define SCAN_B    98

typedef __attribute__((ext_vector_type(8))) short short8;
typedef __attribute__((ext_vector_type(4))) float f32x4;

__device__ __forceinline__ unsigned short bfbits(float x) {
    __bf16 h = (__bf16)x;
    return __builtin_bit_cast(unsigned short, h);
}
__device__ __forceinline__ float bffloat(unsigned short b) {
    return __builtin_bit_cast(float, (unsigned int)b << 16);
}
// 8 fp32 -> bf16 hi/lo fragments
__device__ __forceinline__ void cvt8(const float4& a, const float4& b,
                                     short8& hi, short8& lo) {
    float f[8] = {a.x, a.y, a.z, a.w, b.x, b.y, b.z, b.w};
#pragma unroll
    for (int i = 0; i < 8; ++i) {
        unsigned short hb = bfbits(f[i]);
        hi[i] = (short)hb;
        lo[i] = (short)bfbits(f[i] - bffloat(hb));
    }
}

// ---------------------------------------------------------------------------
// Int histogram of dst (degree count).
__global__ __launch_bounds__(256) void k_hist(const int* __restrict__ dst,
                                              int* __restrict__ ihist) {
    int tid = blockIdx.x * blockDim.x + threadIdx.x;
    int stride = gridDim.x * blockDim.x;
    for (int e = tid; e < N_EDGES; e += stride) atomicAdd(&ihist[dst[e]], 1);
}

// Exclusive scan, pass 1: per-block (512 elems) local scan + block sums.
__global__ __launch_bounds__(512) void k_scan1(const int* __restrict__ ihist,
                                               int* __restrict__ off,
                                               int* __restrict__ bsum) {
    __shared__ int s[512];
    const int t = threadIdx.x, i = blockIdx.x * 512 + t;
    const int v = ihist[i];
    s[t] = v;
    __syncthreads();
    for (int o = 1; o < 512; o <<= 1) {
        int u = (t >= o) ? s[t - o] : 0;
        __syncthreads();
        s[t] += u;
        __syncthreads();
    }
    off[i] = s[t] - v;
    if (t == 511) bsum[blockIdx.x] = s[t];
}

// pass 2: serial exclusive scan of the 98 block sums.
__global__ void k_scan2(const int* __restrict__ bsum, int* __restrict__ bscan) {
    if (threadIdx.x == 0) {
        int acc = 0;
        for (int b = 0; b < SCAN_B; ++b) { bscan[b] = acc; acc += bsum[b]; }
    }
}

// pass 3: add block offsets; duplicate into mutable cursor for the scatter.
__global__ __launch_bounds__(512) void k_scan3(int* __restrict__ off,
                                               const int* __restrict__ bscan,
                                               int* __restrict__ off_cur) {
    const int i = blockIdx.x * 512 + threadIdx.x;
    const int v = off[i] + bscan[i >> 9];
    off[i] = v;
    off_cur[i] = v;
}

// Counting-sort scatter: ssrc/sdsts/seid in dst order.
__global__ __launch_bounds__(256) void k_scatter(const int* __restrict__ src,
                                                 const int* __restrict__ dst,
                                                 int* __restrict__ off_cur,
                                                 int* __restrict__ ssrc,
                                                 int* __restrict__ sdsts,
                                                 int* __restrict__ seid) {
    int tid = blockIdx.x * blockDim.x + threadIdx.x;
    int stride = gridDim.x * blockDim.x;
    for (int e = tid; e < N_EDGES; e += stride) {
        const int d = dst[e];
        const int p = atomicAdd(&off_cur[d], 1);
        ssrc[p] = src[e];
        sdsts[p] = d;
        seid[p] = e;
    }
}

// ---------------------------------------------------------------------------
// ea[E][32] fp32 -> bf16 hi/lo interleaved [E][64], ORIGINAL order (pure
// streaming both sides). 4 lanes per edge.
__global__ __launch_bounds__(256) void k_prepEA(const float* __restrict__ ea,
                                                unsigned short* __restrict__ eaI) {
    int t = blockIdx.x * blockDim.x + threadIdx.x;
    if (t >= N_EDGES * 4) return;
    const int e = t >> 2, q = t & 3;
    float4 a = *(const float4*)(ea + (size_t)e * 32 + q * 8);
    float4 b = *(const float4*)(ea + (size_t)e * 32 + q * 8 + 4);
    short8 hi, lo;
    cvt8(a, b, hi, lo);
    *(short8*)(eaI + (size_t)e * 64 + q * 8) = hi;
    *(short8*)(eaI + (size_t)e * 64 + 32 + q * 8) = lo;
}

// ---------------------------------------------------------------------------
__global__ void k_gcnt(const int* __restrict__ batch, float* __restrict__ gcnt) {
    int g = threadIdx.x;
    if (g >= NUM_GRAPHS) return;
    auto lb = [&](int val) {
        int lo = 0, hi = N_NODES;
        while (lo < hi) { int mid = (lo + hi) >> 1; if (batch[mid] < val) lo = mid + 1; else hi = mid; }
        return lo;
    };
    gcnt[g] = (float)(lb(g + 1) - lb(g));
}

// ---------------------------------------------------------------------------
// Weight prep: W[96][64] fp32 -> Wt hi/lo [64][104] bf16 (transposed, padded).
__global__ void k_prepW(const float* __restrict__ W, unsigned short* __restrict__ Whi,
                        unsigned short* __restrict__ Wlo) {
    int t = blockIdx.x * blockDim.x + threadIdx.x;
    if (t >= 96 * 64) return;
    int k = t >> 6, n = t & 63;
    float x = W[t];
    unsigned short hb = bfbits(x);
    float lof = x - bffloat(hb);
    Whi[n * 104 + k] = hb;
    Wlo[n * 104 + k] = bfbits(lof);
}

// ---------------------------------------------------------------------------
// x[N,64] fp32 -> packed bf16 hi/lo arrays (same row-major layout).
__global__ __launch_bounds__(256) void k_prepX(const float* __restrict__ x,
                                               unsigned short* __restrict__ xhi,
                                               unsigned short* __restrict__ xlo) {
    int t = blockIdx.x * blockDim.x + threadIdx.x;
    if (t >= N_NODES * 8) return;
    const float* r = x + (size_t)t * 8;
    float4 a = ((const float4*)r)[0];
    float4 b = ((const float4*)r)[1];
    short8 hi, lo;
    cvt8(a, b, hi, lo);
    *(short8*)(xhi + (size_t)t * 8) = hi;
    *(short8*)(xlo + (size_t)t * 8) = lo;
}

// ---------------------------------------------------------------------------
// Fused BN-apply (layer1) + layer-2 operand prep.
__global__ __launch_bounds__(256) void k_prepH(const float* __restrict__ h,
                                               const float* __restrict__ ss,
                                               float* __restrict__ hn,
                                               unsigned short* __restrict__ hhi,
                                               unsigned short* __restrict__ hlo) {
    int t = blockIdx.x * blockDim.x + threadIdx.x;
    if (t >= N_NODES * 8) return;
    const int f0 = (t & 7) * 8;
    float4 sca = *(const float4*)(ss + f0);
    float4 scb = *(const float4*)(ss + f0 + 4);
    float4 sha = *(const float4*)(ss + 64 + f0);
    float4 shb = *(const float4*)(ss + 64 + f0 + 4);
    const float* r = h + (size_t)t * 8;
    float4 a = ((const float4*)r)[0];
    float4 b = ((const float4*)r)[1];
    a.x = fmaxf(a.x * sca.x + sha.x, 0.f);
    a.y = fmaxf(a.y * sca.y + sha.y, 0.f);
    a.z = fmaxf(a.z * sca.z + sha.z, 0.f);
    a.w = fmaxf(a.w * sca.w + sha.w, 0.f);
    b.x = fmaxf(b.x * scb.x + shb.x, 0.f);
    b.y = fmaxf(b.y * scb.y + shb.y, 0.f);
    b.z = fmaxf(b.z * scb.z + shb.z, 0.f);
    b.w = fmaxf(b.w * scb.w + shb.w, 0.f);
    ((float4*)(hn + (size_t)t * 8))[0] = a;
    ((float4*)(hn + (size_t)t * 8))[1] = b;
    short8 hi, lo;
    cvt8(a, b, hi, lo);
    *(short8*)(hhi + (size_t)t * 8) = hi;
    *(short8*)(hlo + (size_t)t * 8) = lo;
}

// ---------------------------------------------------------------------------
// Edge message via MFMA; wave-independent, 2 adjacent 16-edge tiles per wave
// (double ILP: all 12 gathers issued up-front; B-frags amortized over both
// tiles). Register-only masked segment reduce + run atomics per tile.
__global__ __launch_bounds__(256) void k_edge(const unsigned short* __restrict__ xhi,
                                              const unsigned short* __restrict__ xlo,
                                              const unsigned short* __restrict__ eaI,
                                              const int*   __restrict__ ssrc,
                                              const int*   __restrict__ sdsts,
                                              const int*   __restrict__ seid,
                                              const unsigned short* __restrict__ Whi,
                                              const unsigned short* __restrict__ Wlo,
                                              const float* __restrict__ bias,
                                              float* __restrict__ aggr) {
    __shared__ int ldstw[4][2][16];

    const int tid  = threadIdx.x;
    const int lane = tid & 63;
    const int w    = tid >> 6;
    const int ew   = (blockIdx.x * 4 + w) * 32;   // wave's 32 edges (2 tiles)

    const int fr   = lane & 15;
    const int hi4  = lane >> 4;
    const int koff = hi4 * 8;
    const int rb   = hi4 * 4;

    const int rA = ew + fr;          // tile 0 row
    const int rB = ew + 16 + fr;     // tile 1 row
    const int sA = ssrc[rA];
    const int sB = ssrc[rB];
    const int iA = seid[rA];
    const int iB = seid[rB];
    if (lane < 32) ldstw[w][lane >> 4][lane & 15] = sdsts[ew + lane];

    // A fragments, both tiles (12 independent 16B gathers)
    short8 aAh0 = *(const short8*)(xhi + (size_t)sA * 64 + koff);
    short8 aAh1 = *(const short8*)(xhi + (size_t)sA * 64 + 32 + koff);
    short8 aAl0 = *(const short8*)(xlo + (size_t)sA * 64 + koff);
    short8 aAl1 = *(const short8*)(xlo + (size_t)sA * 64 + 32 + koff);
    short8 aAh2 = *(const short8*)(eaI + (size_t)iA * 64 + koff);
    short8 aAl2 = *(const short8*)(eaI + (size_t)iA * 64 + 32 + koff);
    short8 aBh0 = *(const short8*)(xhi + (size_t)sB * 64 + koff);
    short8 aBh1 = *(const short8*)(xhi + (size_t)sB * 64 + 32 + koff);
    short8 aBl0 = *(const short8*)(xlo + (size_t)sB * 64 + koff);
    short8 aBl1 = *(const short8*)(xlo + (size_t)sB * 64 + 32 + koff);
    short8 aBh2 = *(const short8*)(eaI + (size_t)iB * 64 + koff);
    short8 aBl2 = *(const short8*)(eaI + (size_t)iB * 64 + 32 + koff);

    f32x4 accA[4], accB[4];
#pragma unroll
    for (int n = 0; n < 4; ++n) {
        const float bv = bias[n * 16 + fr];
        accA[n] = f32x4{bv, bv, bv, bv};
        accB[n] = f32x4{bv, bv, bv, bv};
    }

#pragma unroll
    for (int kb = 0; kb < 3; ++kb) {
        const short8 aA  = (kb == 0) ? aAh0 : (kb == 1) ? aAh1 : aAh2;
        const short8 aAl = (kb == 0) ? aAl0 : (kb == 1) ? aAl1 : aAl2;
        const short8 aB  = (kb == 0) ? aBh0 : (kb == 1) ? aBh1 : aBh2;
        const short8 aBl = (kb == 0) ? aBl0 : (kb == 1) ? aBl1 : aBl2;
#pragma unroll
        for (int nn = 0; nn < 4; ++nn) {
            const short8 bh = *(const short8*)(Whi + (nn * 16 + fr) * 104 + kb * 32 + koff);
            const short8 bl = *(const short8*)(Wlo + (nn * 16 + fr) * 104 + kb * 32 + koff);
            accA[nn] = __builtin_amdgcn_mfma_f32_16x16x32_bf16(aA,  bh, accA[nn], 0, 0, 0);
            accA[nn] = __builtin_amdgcn_mfma_f32_16x16x32_bf16(aAl, bh, accA[nn], 0, 0, 0);
            accA[nn] = __builtin_amdgcn_mfma_f32_16x16x32_bf16(aA,  bl, accA[nn], 0, 0, 0);
            accB[nn] = __builtin_amdgcn_mfma_f32_16x16x32_bf16(aB,  bh, accB[nn], 0, 0, 0);
            accB[nn] = __builtin_amdgcn_mfma_f32_16x16x32_bf16(aBl, bh, accB[nn], 0, 0, 0);
            accB[nn] = __builtin_amdgcn_mfma_f32_16x16x32_bf16(aB,  bl, accB[nn], 0, 0, 0);
        }
    }

    // ReLU in place
#pragma unroll
    for (int n = 0; n < 4; ++n)
#pragma unroll
        for (int j = 0; j < 4; ++j) {
            accA[n][j] = fmaxf(accA[n][j], 0.f);
            accB[n][j] = fmaxf(accB[n][j], 0.f);
        }

    // register segment-reduce per tile (lane holds rows rb..rb+3 of col n*16+fr)
#define SEGREDUCE(TT, ACC)                                                    \
    {                                                                         \
        int r = 0;                                                            \
        while (r < 16) {                                                      \
            const int d = ldstw[w][TT][r];                                    \
            int e2 = r + 1;                                                   \
            while (e2 < 16 && ldstw[w][TT][e2] == d) ++e2;                    \
            float v0 = 0.f, v1 = 0.f, v2 = 0.f, v3 = 0.f;                     \
            _Pragma("unroll")                                                 \
            for (int j = 0; j < 4; ++j) {                                     \
                const bool in = (rb + j >= r) && (rb + j < e2);               \
                v0 += in ? ACC[0][j] : 0.f;                                   \
                v1 += in ? ACC[1][j] : 0.f;                                   \
                v2 += in ? ACC[2][j] : 0.f;                                   \
                v3 += in ? ACC[3][j] : 0.f;                                   \
            }                                                                 \
            v0 += __shfl_xor(v0, 16); v0 += __shfl_xor(v0, 32);               \
            v1 += __shfl_xor(v1, 16); v1 += __shfl_xor(v1, 32);               \
            v2 += __shfl_xor(v2, 16); v2 += __shfl_xor(v2, 32);               \
            v3 += __shfl_xor(v3, 16); v3 += __shfl_xor(v3, 32);               \
            const float val = hi4 == 0 ? v0 : hi4 == 1 ? v1 : hi4 == 2 ? v2 : v3; \
            unsafeAtomicAdd(&aggr[(size_t)d * 64 + lane], val);               \
            r = e2;                                                           \
        }                                                                     \
    }
    SEGREDUCE(0, accA)
    SEGREDUCE(1, accB)
#undef SEGREDUCE
}

// ---------------------------------------------------------------------------
// h = xin @ Wr + aggr/max(deg,1); per-block BN partial sums (no atomics).
__global__ __launch_bounds__(256) void k_combine(const float* __restrict__ xin,
                                                 const float* __restrict__ Wr,
                                                 const float* __restrict__ aggr,
                                                 const int*   __restrict__ ihist,
                                                 float* __restrict__ h,
                                                 float* __restrict__ partial) {
    const int lane = threadIdx.x & 63;
    const int wv   = threadIdx.x >> 6;
    const int wid  = (blockIdx.x * blockDim.x + threadIdx.x) >> 6;
    const int nw   = (gridDim.x * blockDim.x) >> 6;

    float w[64];
#pragma unroll
    for (int k = 0; k < 64; ++k) w[k] = Wr[k * 64 + lane];

    float rs = 0.f, rq = 0.f;
    for (int n = wid; n < N_NODES; n += nw) {
        const float* __restrict__ xr = xin + (size_t)n * 64;
        const float c = fmaxf((float)ihist[n], 1.0f);
        float acc = aggr[(size_t)n * 64 + lane] / c;
#pragma unroll
        for (int k = 0; k < 64; ++k) acc += xr[k] * w[k];
        h[(size_t)n * 64 + lane] = acc;
        rs += acc;
        rq += acc * acc;
    }
    __shared__ float ssum[4][64];
    __shared__ float ssq[4][64];
    ssum[wv][lane] = rs;
    ssq[wv][lane]  = rq;
    __syncthreads();
    if (threadIdx.x < 64) {
        float s = ssum[0][lane] + ssum[1][lane] + ssum[2][lane] + ssum[3][lane];
        partial[blockIdx.x * 128 + lane] = s;
    } else if (threadIdx.x < 128) {
        int l = threadIdx.x - 64;
        float q = ssq[0][l] + ssq[1][l] + ssq[2][l] + ssq[3][l];
        partial[blockIdx.x * 128 + 64 + l] = q;
    }
}

// ---------------------------------------------------------------------------
__global__ void k_bnfin(const float* __restrict__ partial, const float* __restrict__ g,
                        const float* __restrict__ be, float* __restrict__ ss) {
    __shared__ float tot[128];
    int t = threadIdx.x;
    float s = 0.f;
    for (int b = 0; b < NB_COMBINE; ++b) s += partial[b * 128 + t];
    tot[t] = s;
    __syncthreads();
    if (t < 64) {
        float mu  = tot[t] * (1.0f / (float)N_NODES);
        float var = tot[64 + t] * (1.0f / (float)N_NODES) - mu * mu;
        float sc  = g[t] * rsqrtf(var + EPS);
        ss[t]      = sc;
        ss[64 + t] = be[t] - mu * sc;
    }
}

// ---------------------------------------------------------------------------
// Fused BN-apply (layer2) + global mean pool partial sums (sorted-run atomics).
__global__ __launch_bounds__(256) void k_bnpool(const float* __restrict__ h,
                                                const float* __restrict__ ss,
                                                const int* __restrict__ batch,
                                                float* __restrict__ gsum) {
    const int lane = threadIdx.x & 63;
    const int wid  = (blockIdx.x * blockDim.x + threadIdx.x) >> 6;
    const int nw   = (gridDim.x * blockDim.x) >> 6;
    const float sc = ss[lane];
    const float sh = ss[64 + lane];
    const int chunk = (N_NODES + nw - 1) / nw;
    const int n0 = wid * chunk;
    const int n1 = min(n0 + chunk, N_NODES);
    int curg = -1;
    float acc = 0.f;
    for (int n = n0; n < n1; ++n) {
        int g = __builtin_amdgcn_readfirstlane(batch[n]);
        if (g != curg) {
            if (curg >= 0) unsafeAtomicAdd(&gsum[curg * 64 + lane], acc);
            curg = g;
            acc = 0.f;
        }
        acc += fmaxf(h[(size_t)n * 64 + lane] * sc + sh, 0.f);
    }
    if (curg >= 0) unsafeAtomicAdd(&gsum[curg * 64 + lane], acc);
}

// ---------------------------------------------------------------------------
__global__ void k_final(const float* __restrict__ gsum, const float* __restrict__ gcnt,
                        const float* __restrict__ Wro, const float* __restrict__ bro,
                        float* __restrict__ out) {
    int g = blockIdx.x;
    int lane = threadIdx.x;
    float v = gsum[g * 64 + lane] / fmaxf(gcnt[g], 1.0f) * Wro[lane];
#pragma unroll
    for (int off = 32; off > 0; off >>= 1) v += __shfl_down(v, off, 64);
    if (lane == 0) out[g] = v + bro[0];
}

// ---------------------------------------------------------------------------
extern "C" void kernel_launch(void* const* d_in, const int* in_sizes, int n_in,
                              void* d_out, int out_size, void* d_ws, size_t ws_size,
                              hipStream_t stream) {
    (void)in_sizes; (void)n_in; (void)out_size; (void)ws_size;
    const float* x    = (const float*)d_in[0];
    const int*   ei   = (const int*)d_in[1];   // [2, E]
    const float* ea   = (const float*)d_in[2];
    const int*   batch= (const int*)d_in[3];
    const float* Wn1  = (const float*)d_in[4];
    const float* bn1  = (const float*)d_in[5];
    const float* Wr1  = (const float*)d_in[6];
    const float* g1   = (const float*)d_in[7];
    const float* be1  = (const float*)d_in[8];
    const float* Wn2  = (const float*)d_in[9];
    const float* bn2  = (const float*)d_in[10];
    const float* Wr2  = (const float*)d_in[11];
    const float* g2   = (const float*)d_in[12];
    const float* be2  = (const float*)d_in[13];
    const float* Wro  = (const float*)d_in[14];
    const float* bro  = (const float*)d_in[15];
    const int* src = ei;
    const int* dst = ei + N_EDGES;

    float* ws = (float*)d_ws;
    // ---- zeroed region: [gsum | aggr | ihist] ----
    float* gsum   = ws;                               // 3200
    float* aggr   = gsum + 3200;                      // N*64
    int*   ihist  = (int*)(aggr + (size_t)N_NODES * 64); // NHPAD
    const size_t zero_floats = 3200 + (size_t)N_NODES * 64 + NHPAD;
    // ---- non-zeroed ----
    float* h      = (float*)(ihist + NHPAD);
    float* hn     = h + (size_t)N_NODES * 64;
    float* gcnt   = hn + (size_t)N_NODES * 64;        // 64
    float* part1  = gcnt + 64;                        // NB*128
    float* part2  = part1 + NB_COMBINE * 128;
    float* ss1    = part2 + NB_COMBINE * 128;         // 128
    float* ss2    = ss1 + 128;                        // 128
    unsigned short* wb = (unsigned short*)(ss2 + 128);
    unsigned short* Wh1 = wb;                         // 64*104 each
    unsigned short* Wl1 = wb + 6656;
    unsigned short* Wh2 = wb + 13312;
    unsigned short* Wl2 = wb + 19968;
    int* off     = (int*)(wb + 26624);                // NHPAD
    int* off_cur = off + NHPAD;                       // NHPAD
    int* bsum    = off_cur + NHPAD;                   // 128
    int* bscan   = bsum + 128;                        // 128
    int* ssrc    = bscan + 128;                       // E
    int* sdsts   = ssrc + N_EDGES;                    // E
    int* seid    = sdsts + N_EDGES;                   // E
    unsigned short* xhi = (unsigned short*)(seid + N_EDGES); // N*64 each
    unsigned short* xlo = xhi + (size_t)N_NODES * 64;
    unsigned short* hhi = xlo + (size_t)N_NODES * 64;
    unsigned short* hlo = hhi + (size_t)N_NODES * 64;
    unsigned short* eaI = hlo + (size_t)N_NODES * 64;    // E*64

    hipMemsetAsync(d_ws, 0, zero_floats * sizeof(float), stream);

    // ---- edge sort by dst (shared by both layers) ----
    k_hist<<<512, 256, 0, stream>>>(dst, ihist);
    k_scan1<<<SCAN_B, 512, 0, stream>>>(ihist, off, bsum);
    k_scan2<<<1, 64, 0, stream>>>(bsum, bscan);
    k_scan3<<<SCAN_B, 512, 0, stream>>>(off, bscan, off_cur);
    k_scatter<<<512, 256, 0, stream>>>(src, dst, off_cur, ssrc, sdsts, seid);
    k_prepEA<<<N_EDGES * 4 / 256, 256, 0, stream>>>(ea, eaI);

    k_gcnt<<<1, 64, 0, stream>>>(batch, gcnt);
    k_prepW<<<24, 256, 0, stream>>>(Wn1, Wh1, Wl1);
    k_prepW<<<24, 256, 0, stream>>>(Wn2, Wh2, Wl2);
    k_prepX<<<(N_NODES * 8 + 255) / 256, 256, 0, stream>>>(x, xhi, xlo);

    // ---- layer 1 ----
    k_edge<<<N_EDGES / 128, 256, 0, stream>>>(xhi, xlo, eaI, ssrc, sdsts, seid, Wh1, Wl1, bn1, aggr);
    k_combine<<<NB_COMBINE, 256, 0, stream>>>(x, Wr1, aggr, ihist, h, part1);
    k_bnfin<<<1, 128, 0, stream>>>(part1, g1, be1, ss1);
    k_prepH<<<(N_NODES * 8 + 255) / 256, 256, 0, stream>>>(h, ss1, hn, hhi, hlo);

    // ---- layer 2 ----
    hipMemsetAsync(aggr, 0, (size_t)N_NODES * 64 * sizeof(float), stream);
    k_edge<<<N_EDGES / 128, 256, 0, stream>>>(hhi, hlo, eaI, ssrc, sdsts, seid, Wh2, Wl2, bn2, aggr);
    k_combine<<<NB_COMBINE, 256, 0, stream>>>(hn, Wr2, aggr, ihist, h, part2);
    k_bnfin<<<1, 128, 0, stream>>>(part2, g2, be2, ss2);

    // ---- readout (BN-apply fused into pool) ----
    k_bnpool<<<256, 256, 0, stream>>>(h, ss2, batch, gsum);
    k_final<<<NUM_GRAPHS, 64, 0, stream>>>(gsum, gcnt, Wro, bro, (float*)d_out);
}

// Round 11
// 416.613 us; speedup vs baseline: 1.4638x; 1.1577x over previous
//
#include <hip/hip_runtime.h>

#define N_NODES   50000
#define N_EDGES   800000
#define HID       64
#define NUM_GRAPHS 50
#define EPS       1e-5f
#define NB_COMBINE 256
#define NHPAD     50176          // 98 * 512, padded histogram/scan size
#define SCAN_B    98

typedef __attribute__((ext_vector_type(8))) short short8;
typedef __attribute__((ext_vector_type(4))) float f32x4;

__device__ __forceinline__ unsigned short bfbits(float x) {
    __bf16 h = (__bf16)x;
    return __builtin_bit_cast(unsigned short, h);
}
// 8 fp32 -> 8 bf16 (single product, RTN)
__device__ __forceinline__ short8 cvt8hi(const float4& a, const float4& b) {
    float f[8] = {a.x, a.y, a.z, a.w, b.x, b.y, b.z, b.w};
    short8 hi;
#pragma unroll
    for (int i = 0; i < 8; ++i) hi[i] = (short)bfbits(f[i]);
    return hi;
}

// ---------------------------------------------------------------------------
// Int histogram of dst (degree count).
__global__ __launch_bounds__(256) void k_hist(const int* __restrict__ dst,
                                              int* __restrict__ ihist) {
    int tid = blockIdx.x * blockDim.x + threadIdx.x;
    int stride = gridDim.x * blockDim.x;
    for (int e = tid; e < N_EDGES; e += stride) atomicAdd(&ihist[dst[e]], 1);
}

// Exclusive scan, pass 1: per-block (512 elems) local scan + block sums.
__global__ __launch_bounds__(512) void k_scan1(const int* __restrict__ ihist,
                                               int* __restrict__ off,
                                               int* __restrict__ bsum) {
    __shared__ int s[512];
    const int t = threadIdx.x, i = blockIdx.x * 512 + t;
    const int v = ihist[i];
    s[t] = v;
    __syncthreads();
    for (int o = 1; o < 512; o <<= 1) {
        int u = (t >= o) ? s[t - o] : 0;
        __syncthreads();
        s[t] += u;
        __syncthreads();
    }
    off[i] = s[t] - v;
    if (t == 511) bsum[blockIdx.x] = s[t];
}

// pass 2: serial exclusive scan of the 98 block sums.
__global__ void k_scan2(const int* __restrict__ bsum, int* __restrict__ bscan) {
    if (threadIdx.x == 0) {
        int acc = 0;
        for (int b = 0; b < SCAN_B; ++b) { bscan[b] = acc; acc += bsum[b]; }
    }
}

// pass 3: add block offsets; duplicate into mutable cursor for the scatter.
__global__ __launch_bounds__(512) void k_scan3(int* __restrict__ off,
                                               const int* __restrict__ bscan,
                                               int* __restrict__ off_cur) {
    const int i = blockIdx.x * 512 + threadIdx.x;
    const int v = off[i] + bscan[i >> 9];
    off[i] = v;
    off_cur[i] = v;
}

// Counting-sort scatter: packed edge record (src|dst<<16, eid) in dst order.
__global__ __launch_bounds__(256) void k_scatter(const int* __restrict__ src,
                                                 const int* __restrict__ dst,
                                                 int* __restrict__ off_cur,
                                                 int2* __restrict__ epk) {
    int tid = blockIdx.x * blockDim.x + threadIdx.x;
    int stride = gridDim.x * blockDim.x;
    for (int e = tid; e < N_EDGES; e += stride) {
        const int d = dst[e];
        const int p = atomicAdd(&off_cur[d], 1);
        epk[p] = int2{src[e] | (d << 16), e};
    }
}

// ---------------------------------------------------------------------------
// ea[E][32] fp32 -> bf16 [E][32], original order (pure streaming).
__global__ __launch_bounds__(256) void k_prepEA(const float* __restrict__ ea,
                                                unsigned short* __restrict__ eaB) {
    int t = blockIdx.x * blockDim.x + threadIdx.x;
    if (t >= N_EDGES * 4) return;
    float4 a = *(const float4*)(ea + (size_t)t * 8);
    float4 b = *(const float4*)(ea + (size_t)t * 8 + 4);
    *(short8*)(eaB + (size_t)t * 8) = cvt8hi(a, b);
}

// ---------------------------------------------------------------------------
__global__ void k_gcnt(const int* __restrict__ batch, float* __restrict__ gcnt) {
    int g = threadIdx.x;
    if (g >= NUM_GRAPHS) return;
    auto lb = [&](int val) {
        int lo = 0, hi = N_NODES;
        while (lo < hi) { int mid = (lo + hi) >> 1; if (batch[mid] < val) lo = mid + 1; else hi = mid; }
        return lo;
    };
    gcnt[g] = (float)(lb(g + 1) - lb(g));
}

// ---------------------------------------------------------------------------
// Weight prep: W[96][64] fp32 -> Wb [64][104] bf16 (transposed, padded).
__global__ void k_prepW(const float* __restrict__ W, unsigned short* __restrict__ Wb) {
    int t = blockIdx.x * blockDim.x + threadIdx.x;
    if (t >= 96 * 64) return;
    int k = t >> 6, n = t & 63;
    Wb[n * 104 + k] = bfbits(W[t]);
}

// ---------------------------------------------------------------------------
// x[N,64] fp32 -> bf16 [N,64].
__global__ __launch_bounds__(256) void k_prepX(const float* __restrict__ x,
                                               unsigned short* __restrict__ xb) {
    int t = blockIdx.x * blockDim.x + threadIdx.x;
    if (t >= N_NODES * 8) return;
    float4 a = ((const float4*)(x + (size_t)t * 8))[0];
    float4 b = ((const float4*)(x + (size_t)t * 8))[1];
    *(short8*)(xb + (size_t)t * 8) = cvt8hi(a, b);
}

// ---------------------------------------------------------------------------
// Fused BN-apply (layer1): hn = relu(h*sc+sh) fp32 + bf16 copy for layer-2 edge.
__global__ __launch_bounds__(256) void k_prepH(const float* __restrict__ h,
                                               const float* __restrict__ ss,
                                               float* __restrict__ hn,
                                               unsigned short* __restrict__ hb) {
    int t = blockIdx.x * blockDim.x + threadIdx.x;
    if (t >= N_NODES * 8) return;
    const int f0 = (t & 7) * 8;
    float4 sca = *(const float4*)(ss + f0);
    float4 scb = *(const float4*)(ss + f0 + 4);
    float4 sha = *(const float4*)(ss + 64 + f0);
    float4 shb = *(const float4*)(ss + 64 + f0 + 4);
    const float* r = h + (size_t)t * 8;
    float4 a = ((const float4*)r)[0];
    float4 b = ((const float4*)r)[1];
    a.x = fmaxf(a.x * sca.x + sha.x, 0.f);
    a.y = fmaxf(a.y * sca.y + sha.y, 0.f);
    a.z = fmaxf(a.z * sca.z + sha.z, 0.f);
    a.w = fmaxf(a.w * sca.w + sha.w, 0.f);
    b.x = fmaxf(b.x * scb.x + shb.x, 0.f);
    b.y = fmaxf(b.y * scb.y + shb.y, 0.f);
    b.z = fmaxf(b.z * scb.z + shb.z, 0.f);
    b.w = fmaxf(b.w * scb.w + shb.w, 0.f);
    ((float4*)(hn + (size_t)t * 8))[0] = a;
    ((float4*)(hn + (size_t)t * 8))[1] = b;
    *(short8*)(hb + (size_t)t * 8) = cvt8hi(a, b);
}

// ---------------------------------------------------------------------------
// Edge message via MFMA, pure bf16 operands (fp32 accum). Wave-independent,
// 2 adjacent 16-edge tiles per wave; 12 MFMA/tile; packed idx (one 8B load
// per row); register-only masked segment reduce + run atomics per tile.
__global__ __launch_bounds__(256) void k_edge(const unsigned short* __restrict__ xb,
                                              const unsigned short* __restrict__ eaB,
                                              const int2* __restrict__ epk,
                                              const unsigned short* __restrict__ Wb,
                                              const float* __restrict__ bias,
                                              float* __restrict__ aggr) {
    __shared__ int ldstw[4][2][16];

    const int tid  = threadIdx.x;
    const int lane = tid & 63;
    const int w    = tid >> 6;
    const int ew   = (blockIdx.x * 4 + w) * 32;   // wave's 32 edges (2 tiles)

    const int fr   = lane & 15;
    const int hi4  = lane >> 4;
    const int koff = hi4 * 8;
    const int rb   = hi4 * 4;

    if (lane < 32)
        ldstw[w][lane >> 4][lane & 15] = ((unsigned)epk[ew + lane].x) >> 16;

    const int2 eA = epk[ew + fr];
    const int2 eB = epk[ew + 16 + fr];
    const int sA = eA.x & 0xffff, iA = eA.y;
    const int sB = eB.x & 0xffff, iB = eB.y;

    // A fragments, both tiles (6 independent 16B gathers)
    short8 aA0 = *(const short8*)(xb + (size_t)sA * 64 + koff);
    short8 aA1 = *(const short8*)(xb + (size_t)sA * 64 + 32 + koff);
    short8 aA2 = *(const short8*)(eaB + (size_t)iA * 32 + koff);
    short8 aB0 = *(const short8*)(xb + (size_t)sB * 64 + koff);
    short8 aB1 = *(const short8*)(xb + (size_t)sB * 64 + 32 + koff);
    short8 aB2 = *(const short8*)(eaB + (size_t)iB * 32 + koff);

    f32x4 accA[4], accB[4];
#pragma unroll
    for (int n = 0; n < 4; ++n) {
        const float bv = bias[n * 16 + fr];
        accA[n] = f32x4{bv, bv, bv, bv};
        accB[n] = f32x4{bv, bv, bv, bv};
    }

#pragma unroll
    for (int kb = 0; kb < 3; ++kb) {
        const short8 aA = (kb == 0) ? aA0 : (kb == 1) ? aA1 : aA2;
        const short8 aB = (kb == 0) ? aB0 : (kb == 1) ? aB1 : aB2;
#pragma unroll
        for (int nn = 0; nn < 4; ++nn) {
            const short8 bh = *(const short8*)(Wb + (nn * 16 + fr) * 104 + kb * 32 + koff);
            accA[nn] = __builtin_amdgcn_mfma_f32_16x16x32_bf16(aA, bh, accA[nn], 0, 0, 0);
            accB[nn] = __builtin_amdgcn_mfma_f32_16x16x32_bf16(aB, bh, accB[nn], 0, 0, 0);
        }
    }

    // ReLU in place
#pragma unroll
    for (int n = 0; n < 4; ++n)
#pragma unroll
        for (int j = 0; j < 4; ++j) {
            accA[n][j] = fmaxf(accA[n][j], 0.f);
            accB[n][j] = fmaxf(accB[n][j], 0.f);
        }

    // register segment-reduce per tile (lane holds rows rb..rb+3 of col n*16+fr)
#define SEGREDUCE(TT, ACC)                                                    \
    {                                                                         \
        int r = 0;                                                            \
        while (r < 16) {                                                      \
            const int d = ldstw[w][TT][r];                                    \
            int e2 = r + 1;                                                   \
            while (e2 < 16 && ldstw[w][TT][e2] == d) ++e2;                    \
            float v0 = 0.f, v1 = 0.f, v2 = 0.f, v3 = 0.f;                     \
            _Pragma("unroll")                                                 \
            for (int j = 0; j < 4; ++j) {                                     \
                const bool in = (rb + j >= r) && (rb + j < e2);               \
                v0 += in ? ACC[0][j] : 0.f;                                   \
                v1 += in ? ACC[1][j] : 0.f;                                   \
                v2 += in ? ACC[2][j] : 0.f;                                   \
                v3 += in ? ACC[3][j] : 0.f;                                   \
            }                                                                 \
            v0 += __shfl_xor(v0, 16); v0 += __shfl_xor(v0, 32);               \
            v1 += __shfl_xor(v1, 16); v1 += __shfl_xor(v1, 32);               \
            v2 += __shfl_xor(v2, 16); v2 += __shfl_xor(v2, 32);               \
            v3 += __shfl_xor(v3, 16); v3 += __shfl_xor(v3, 32);               \
            const float val = hi4 == 0 ? v0 : hi4 == 1 ? v1 : hi4 == 2 ? v2 : v3; \
            unsafeAtomicAdd(&aggr[(size_t)d * 64 + lane], val);               \
            r = e2;                                                           \
        }                                                                     \
    }
    SEGREDUCE(0, accA)
    SEGREDUCE(1, accB)
#undef SEGREDUCE
}

// ---------------------------------------------------------------------------
// h = xin @ Wr + aggr/max(deg,1); per-block BN partial sums (no atomics).
__global__ __launch_bounds__(256) void k_combine(const float* __restrict__ xin,
                                                 const float* __restrict__ Wr,
                                                 const float* __restrict__ aggr,
                                                 const int*   __restrict__ ihist,
                                                 float* __restrict__ h,
                                                 float* __restrict__ partial) {
    const int lane = threadIdx.x & 63;
    const int wv   = threadIdx.x >> 6;
    const int wid  = (blockIdx.x * blockDim.x + threadIdx.x) >> 6;
    const int nw   = (gridDim.x * blockDim.x) >> 6;

    float w[64];
#pragma unroll
    for (int k = 0; k < 64; ++k) w[k] = Wr[k * 64 + lane];

    float rs = 0.f, rq = 0.f;
    for (int n = wid; n < N_NODES; n += nw) {
        const float* __restrict__ xr = xin + (size_t)n * 64;
        const float c = fmaxf((float)ihist[n], 1.0f);
        float acc = aggr[(size_t)n * 64 + lane] / c;
#pragma unroll
        for (int k = 0; k < 64; ++k) acc += xr[k] * w[k];
        h[(size_t)n * 64 + lane] = acc;
        rs += acc;
        rq += acc * acc;
    }
    __shared__ float ssum[4][64];
    __shared__ float ssq[4][64];
    ssum[wv][lane] = rs;
    ssq[wv][lane]  = rq;
    __syncthreads();
    if (threadIdx.x < 64) {
        float s = ssum[0][lane] + ssum[1][lane] + ssum[2][lane] + ssum[3][lane];
        partial[blockIdx.x * 128 + lane] = s;
    } else if (threadIdx.x < 128) {
        int l = threadIdx.x - 64;
        float q = ssq[0][l] + ssq[1][l] + ssq[2][l] + ssq[3][l];
        partial[blockIdx.x * 128 + 64 + l] = q;
    }
}

// ---------------------------------------------------------------------------
__global__ void k_bnfin(const float* __restrict__ partial, const float* __restrict__ g,
                        const float* __restrict__ be, float* __restrict__ ss) {
    __shared__ float tot[128];
    int t = threadIdx.x;
    float s = 0.f;
    for (int b = 0; b < NB_COMBINE; ++b) s += partial[b * 128 + t];
    tot[t] = s;
    __syncthreads();
    if (t < 64) {
        float mu  = tot[t] * (1.0f / (float)N_NODES);
        float var = tot[64 + t] * (1.0f / (float)N_NODES) - mu * mu;
        float sc  = g[t] * rsqrtf(var + EPS);
        ss[t]      = sc;
        ss[64 + t] = be[t] - mu * sc;
    }
}

// ---------------------------------------------------------------------------
// Fused BN-apply (layer2) + global mean pool partial sums (sorted-run atomics).
__global__ __launch_bounds__(256) void k_bnpool(const float* __restrict__ h,
                                                const float* __restrict__ ss,
                                                const int* __restrict__ batch,
                                                float* __restrict__ gsum) {
    const int lane = threadIdx.x & 63;
    const int wid  = (blockIdx.x * blockDim.x + threadIdx.x) >> 6;
    const int nw   = (gridDim.x * blockDim.x) >> 6;
    const float sc = ss[lane];
    const float sh = ss[64 + lane];
    const int chunk = (N_NODES + nw - 1) / nw;
    const int n0 = wid * chunk;
    const int n1 = min(n0 + chunk, N_NODES);
    int curg = -1;
    float acc = 0.f;
    for (int n = n0; n < n1; ++n) {
        int g = __builtin_amdgcn_readfirstlane(batch[n]);
        if (g != curg) {
            if (curg >= 0) unsafeAtomicAdd(&gsum[curg * 64 + lane], acc);
            curg = g;
            acc = 0.f;
        }
        acc += fmaxf(h[(size_t)n * 64 + lane] * sc + sh, 0.f);
    }
    if (curg >= 0) unsafeAtomicAdd(&gsum[curg * 64 + lane], acc);
}

// ---------------------------------------------------------------------------
__global__ void k_final(const float* __restrict__ gsum, const float* __restrict__ gcnt,
                        const float* __restrict__ Wro, const float* __restrict__ bro,
                        float* __restrict__ out) {
    int g = blockIdx.x;
    int lane = threadIdx.x;
    float v = gsum[g * 64 + lane] / fmaxf(gcnt[g], 1.0f) * Wro[lane];
#pragma unroll
    for (int off = 32; off > 0; off >>= 1) v += __shfl_down(v, off, 64);
    if (lane == 0) out[g] = v + bro[0];
}

// ---------------------------------------------------------------------------
extern "C" void kernel_launch(void* const* d_in, const int* in_sizes, int n_in,
                              void* d_out, int out_size, void* d_ws, size_t ws_size,
                              hipStream_t stream) {
    (void)in_sizes; (void)n_in; (void)out_size; (void)ws_size;
    const float* x    = (const float*)d_in[0];
    const int*   ei   = (const int*)d_in[1];   // [2, E]
    const float* ea   = (const float*)d_in[2];
    const int*   batch= (const int*)d_in[3];
    const float* Wn1  = (const float*)d_in[4];
    const float* bn1  = (const float*)d_in[5];
    const float* Wr1  = (const float*)d_in[6];
    const float* g1   = (const float*)d_in[7];
    const float* be1  = (const float*)d_in[8];
    const float* Wn2  = (const float*)d_in[9];
    const float* bn2  = (const float*)d_in[10];
    const float* Wr2  = (const float*)d_in[11];
    const float* g2   = (const float*)d_in[12];
    const float* be2  = (const float*)d_in[13];
    const float* Wro  = (const float*)d_in[14];
    const float* bro  = (const float*)d_in[15];
    const int* src = ei;
    const int* dst = ei + N_EDGES;

    float* ws = (float*)d_ws;
    // ---- zeroed region: [gsum | aggr | ihist] ----
    float* gsum   = ws;                               // 3200
    float* aggr   = gsum + 3200;                      // N*64
    int*   ihist  = (int*)(aggr + (size_t)N_NODES * 64); // NHPAD
    const size_t zero_floats = 3200 + (size_t)N_NODES * 64 + NHPAD;
    // ---- non-zeroed ----
    float* h      = (float*)(ihist + NHPAD);
    float* hn     = h + (size_t)N_NODES * 64;
    float* gcnt   = hn + (size_t)N_NODES * 64;        // 64
    float* part1  = gcnt + 64;                        // NB*128
    float* part2  = part1 + NB_COMBINE * 128;
    float* ss1    = part2 + NB_COMBINE * 128;         // 128
    float* ss2    = ss1 + 128;                        // 128
    unsigned short* Wb1 = (unsigned short*)(ss2 + 128); // 64*104 ushort each
    unsigned short* Wb2 = Wb1 + 6656;
    int* off     = (int*)(Wb2 + 6656);                // NHPAD
    int* off_cur = off + NHPAD;                       // NHPAD
    int* bsum    = off_cur + NHPAD;                   // 128
    int* bscan   = bsum + 128;                        // 128
    int2* epk    = (int2*)(bscan + 128);              // E int2 (8B-aligned)
    unsigned short* xb  = (unsigned short*)(epk + N_EDGES); // N*64
    unsigned short* hb  = xb + (size_t)N_NODES * 64;        // N*64
    unsigned short* eaB = hb + (size_t)N_NODES * 64;        // E*32

    hipMemsetAsync(d_ws, 0, zero_floats * sizeof(float), stream);

    // ---- edge sort by dst (shared by both layers) ----
    k_hist<<<512, 256, 0, stream>>>(dst, ihist);
    k_scan1<<<SCAN_B, 512, 0, stream>>>(ihist, off, bsum);
    k_scan2<<<1, 64, 0, stream>>>(bsum, bscan);
    k_scan3<<<SCAN_B, 512, 0, stream>>>(off, bscan, off_cur);
    k_scatter<<<512, 256, 0, stream>>>(src, dst, off_cur, epk);
    k_prepEA<<<N_EDGES * 4 / 256, 256, 0, stream>>>(ea, eaB);

    k_gcnt<<<1, 64, 0, stream>>>(batch, gcnt);
    k_prepW<<<24, 256, 0, stream>>>(Wn1, Wb1);
    k_prepW<<<24, 256, 0, stream>>>(Wn2, Wb2);
    k_prepX<<<(N_NODES * 8 + 255) / 256, 256, 0, stream>>>(x, xb);

    // ---- layer 1 ----
    k_edge<<<N_EDGES / 128, 256, 0, stream>>>(xb, eaB, epk, Wb1, bn1, aggr);
    k_combine<<<NB_COMBINE, 256, 0, stream>>>(x, Wr1, aggr, ihist, h, part1);
    k_bnfin<<<1, 128, 0, stream>>>(part1, g1, be1, ss1);
    k_prepH<<<(N_NODES * 8 + 255) / 256, 256, 0, stream>>>(h, ss1, hn, hb);

    // ---- layer 2 ----
    hipMemsetAsync(aggr, 0, (size_t)N_NODES * 64 * sizeof(float), stream);
    k_edge<<<N_EDGES / 128, 256, 0, stream>>>(hb, eaB, epk, Wb2, bn2, aggr);
    k_combine<<<NB_COMBINE, 256, 0, stream>>>(hn, Wr2, aggr, ihist, h, part2);
    k_bnfin<<<1, 128, 0, stream>>>(part2, g2, be2, ss2);

    // ---- readout (BN-apply fused into pool) ----
    k_bnpool<<<256, 256, 0, stream>>>(h, ss2, batch, gsum);
    k_final<<<NUM_GRAPHS, 64, 0, stream>>>(gsum, gcnt, Wro, bro, (float*)d_out);
}

// Round 12
// 379.609 us; speedup vs baseline: 1.6065x; 1.0975x over previous
//
#include <hip/hip_runtime.h>

#define N_NODES   50000
#define N_EDGES   800000
#define HID       64
#define NUM_GRAPHS 50
#define EPS       1e-5f
#define NB_COMBINE 256
#define NHPAD     50176          // 98 * 512, padded histogram/scan size
#define SCAN_B    98
#define NBKT      98             // coarse buckets = dst >> 9 (512 nodes each)
#define BSH       9
#define BATCH     2048           // edges per k_bin block (8 per thread)

typedef __attribute__((ext_vector_type(8))) short short8;
typedef __attribute__((ext_vector_type(4))) float f32x4;

__device__ __forceinline__ unsigned short bfbits(float x) {
    __bf16 h = (__bf16)x;
    return __builtin_bit_cast(unsigned short, h);
}
// 8 fp32 -> 8 bf16 (RTN)
__device__ __forceinline__ short8 cvt8hi(const float4& a, const float4& b) {
    float f[8] = {a.x, a.y, a.z, a.w, b.x, b.y, b.z, b.w};
    short8 hi;
#pragma unroll
    for (int i = 0; i < 8; ++i) hi[i] = (short)bfbits(f[i]);
    return hi;
}

// ---------------------------------------------------------------------------
// Int histogram of dst (degree count).
__global__ __launch_bounds__(256) void k_hist(const int* __restrict__ dst,
                                              int* __restrict__ ihist) {
    int tid = blockIdx.x * blockDim.x + threadIdx.x;
    int stride = gridDim.x * blockDim.x;
    for (int e = tid; e < N_EDGES; e += stride) atomicAdd(&ihist[dst[e]], 1);
}

// Exclusive scan, pass 1: per-block (512 elems) local scan + block sums.
__global__ __launch_bounds__(512) void k_scan1(const int* __restrict__ ihist,
                                               int* __restrict__ off,
                                               int* __restrict__ bsum) {
    __shared__ int s[512];
    const int t = threadIdx.x, i = blockIdx.x * 512 + t;
    const int v = ihist[i];
    s[t] = v;
    __syncthreads();
    for (int o = 1; o < 512; o <<= 1) {
        int u = (t >= o) ? s[t - o] : 0;
        __syncthreads();
        s[t] += u;
        __syncthreads();
    }
    off[i] = s[t] - v;
    if (t == 511) bsum[blockIdx.x] = s[t];
}

// pass 2: serial exclusive scan of the 98 block sums.
__global__ void k_scan2(const int* __restrict__ bsum, int* __restrict__ bscan) {
    if (threadIdx.x == 0) {
        int acc = 0;
        for (int b = 0; b < SCAN_B; ++b) { bscan[b] = acc; acc += bsum[b]; }
    }
}

// pass 3: add block offsets in place.
__global__ __launch_bounds__(512) void k_scan3(int* __restrict__ off,
                                               const int* __restrict__ bscan) {
    const int i = blockIdx.x * 512 + threadIdx.x;
    off[i] += bscan[i >> 9];
}

// bucket cursors = node-scan value at each bucket's first node.
__global__ void k_bcur(const int* __restrict__ off, int* __restrict__ bcur) {
    int b = threadIdx.x;
    if (b < NBKT) bcur[b] = off[b << BSH];
}

// ---------------------------------------------------------------------------
// Pass 1: bin edges into 98 coarse buckets (dst>>9). LDS histogram + one
// global cursor reservation per (block,bucket) -> ~21-record contiguous
// chunks per bucket (write-amp ~1.3x instead of 8x).
__global__ __launch_bounds__(256) void k_bin(const int* __restrict__ src,
                                             const int* __restrict__ dst,
                                             int* __restrict__ bcur,
                                             int2* __restrict__ binned) {
    __shared__ int bh[NBKT], gb[NBKT];
    const int tid = threadIdx.x;
    const int base = blockIdx.x * BATCH + tid * 8;
    int2 rec[8]; int bk[8]; bool val[8];
#pragma unroll
    for (int j = 0; j < 8; ++j) {
        const int e = base + j;
        val[j] = e < N_EDGES;
        if (val[j]) {
            const int d = dst[e];
            rec[j] = int2{src[e] | (d << 16), e};
            bk[j] = d >> BSH;
        } else bk[j] = 0;
    }
    if (tid < NBKT) bh[tid] = 0;
    __syncthreads();
#pragma unroll
    for (int j = 0; j < 8; ++j) if (val[j]) atomicAdd(&bh[bk[j]], 1);
    __syncthreads();
    if (tid < NBKT) { gb[tid] = atomicAdd(&bcur[tid], bh[tid]); bh[tid] = 0; }
    __syncthreads();
#pragma unroll
    for (int j = 0; j < 8; ++j)
        if (val[j]) {
            const int r = atomicAdd(&bh[bk[j]], 1);
            binned[gb[bk[j]] + r] = rec[j];
        }
}

// ---------------------------------------------------------------------------
// Pass 2: one block per bucket; per-node LDS cursors; scatter within the
// bucket's contiguous epk span (single XCD owns all its lines -> L2 merge).
__global__ __launch_bounds__(256) void k_sortb(const int2* __restrict__ binned,
                                               const int* __restrict__ off,
                                               int2* __restrict__ epk) {
    __shared__ int cur[512];
    const int b = blockIdx.x;
    const int nbase = b << BSH;
    const int tid = threadIdx.x;
    for (int i = tid; i < 512; i += 256) cur[i] = off[nbase + i];
    const int start = off[nbase];
    const int end = (b == NBKT - 1) ? N_EDGES : off[nbase + 512];
    __syncthreads();
    for (int p = start + tid; p < end; p += 256) {
        const int2 r = binned[p];
        const int d = ((unsigned)r.x) >> 16;
        const int pos = atomicAdd(&cur[d - nbase], 1);
        epk[pos] = r;
    }
}

// ---------------------------------------------------------------------------
// ea[E][32] fp32 -> bf16 [E][32], original order (pure streaming).
__global__ __launch_bounds__(256) void k_prepEA(const float* __restrict__ ea,
                                                unsigned short* __restrict__ eaB) {
    int t = blockIdx.x * blockDim.x + threadIdx.x;
    if (t >= N_EDGES * 4) return;
    float4 a = *(const float4*)(ea + (size_t)t * 8);
    float4 b = *(const float4*)(ea + (size_t)t * 8 + 4);
    *(short8*)(eaB + (size_t)t * 8) = cvt8hi(a, b);
}

// ---------------------------------------------------------------------------
__global__ void k_gcnt(const int* __restrict__ batch, float* __restrict__ gcnt) {
    int g = threadIdx.x;
    if (g >= NUM_GRAPHS) return;
    auto lb = [&](int val) {
        int lo = 0, hi = N_NODES;
        while (lo < hi) { int mid = (lo + hi) >> 1; if (batch[mid] < val) lo = mid + 1; else hi = mid; }
        return lo;
    };
    gcnt[g] = (float)(lb(g + 1) - lb(g));
}

// ---------------------------------------------------------------------------
// Weight prep: W[96][64] fp32 -> Wb [64][104] bf16 (transposed, padded).
__global__ void k_prepW(const float* __restrict__ W, unsigned short* __restrict__ Wb) {
    int t = blockIdx.x * blockDim.x + threadIdx.x;
    if (t >= 96 * 64) return;
    int k = t >> 6, n = t & 63;
    Wb[n * 104 + k] = bfbits(W[t]);
}

// ---------------------------------------------------------------------------
// x[N,64] fp32 -> bf16 [N,64].
__global__ __launch_bounds__(256) void k_prepX(const float* __restrict__ x,
                                               unsigned short* __restrict__ xb) {
    int t = blockIdx.x * blockDim.x + threadIdx.x;
    if (t >= N_NODES * 8) return;
    float4 a = ((const float4*)(x + (size_t)t * 8))[0];
    float4 b = ((const float4*)(x + (size_t)t * 8))[1];
    *(short8*)(xb + (size_t)t * 8) = cvt8hi(a, b);
}

// ---------------------------------------------------------------------------
// Fused BN-apply (layer1): hn = relu(h*sc+sh) fp32 + bf16 copy for layer-2 edge.
__global__ __launch_bounds__(256) void k_prepH(const float* __restrict__ h,
                                               const float* __restrict__ ss,
                                               float* __restrict__ hn,
                                               unsigned short* __restrict__ hb) {
    int t = blockIdx.x * blockDim.x + threadIdx.x;
    if (t >= N_NODES * 8) return;
    const int f0 = (t & 7) * 8;
    float4 sca = *(const float4*)(ss + f0);
    float4 scb = *(const float4*)(ss + f0 + 4);
    float4 sha = *(const float4*)(ss + 64 + f0);
    float4 shb = *(const float4*)(ss + 64 + f0 + 4);
    const float* r = h + (size_t)t * 8;
    float4 a = ((const float4*)r)[0];
    float4 b = ((const float4*)r)[1];
    a.x = fmaxf(a.x * sca.x + sha.x, 0.f);
    a.y = fmaxf(a.y * sca.y + sha.y, 0.f);
    a.z = fmaxf(a.z * sca.z + sha.z, 0.f);
    a.w = fmaxf(a.w * sca.w + sha.w, 0.f);
    b.x = fmaxf(b.x * scb.x + shb.x, 0.f);
    b.y = fmaxf(b.y * scb.y + shb.y, 0.f);
    b.z = fmaxf(b.z * scb.z + shb.z, 0.f);
    b.w = fmaxf(b.w * scb.w + shb.w, 0.f);
    ((float4*)(hn + (size_t)t * 8))[0] = a;
    ((float4*)(hn + (size_t)t * 8))[1] = b;
    *(short8*)(hb + (size_t)t * 8) = cvt8hi(a, b);
}

// ---------------------------------------------------------------------------
// Edge message via MFMA, pure bf16 operands (fp32 accum). Wave-independent,
// 2 adjacent 16-edge tiles per wave; 12 MFMA/tile; packed idx (one 8B load
// per row); register-only masked segment reduce + run atomics per tile.
__global__ __launch_bounds__(256) void k_edge(const unsigned short* __restrict__ xb,
                                              const unsigned short* __restrict__ eaB,
                                              const int2* __restrict__ epk,
                                              const unsigned short* __restrict__ Wb,
                                              const float* __restrict__ bias,
                                              float* __restrict__ aggr) {
    __shared__ int ldstw[4][2][16];

    const int tid  = threadIdx.x;
    const int lane = tid & 63;
    const int w    = tid >> 6;
    const int ew   = (blockIdx.x * 4 + w) * 32;   // wave's 32 edges (2 tiles)

    const int fr   = lane & 15;
    const int hi4  = lane >> 4;
    const int koff = hi4 * 8;
    const int rb   = hi4 * 4;

    if (lane < 32)
        ldstw[w][lane >> 4][lane & 15] = ((unsigned)epk[ew + lane].x) >> 16;

    const int2 eA = epk[ew + fr];
    const int2 eB = epk[ew + 16 + fr];
    const int sA = eA.x & 0xffff, iA = eA.y;
    const int sB = eB.x & 0xffff, iB = eB.y;

    // A fragments, both tiles (6 independent 16B gathers)
    short8 aA0 = *(const short8*)(xb + (size_t)sA * 64 + koff);
    short8 aA1 = *(const short8*)(xb + (size_t)sA * 64 + 32 + koff);
    short8 aA2 = *(const short8*)(eaB + (size_t)iA * 32 + koff);
    short8 aB0 = *(const short8*)(xb + (size_t)sB * 64 + koff);
    short8 aB1 = *(const short8*)(xb + (size_t)sB * 64 + 32 + koff);
    short8 aB2 = *(const short8*)(eaB + (size_t)iB * 32 + koff);

    f32x4 accA[4], accB[4];
#pragma unroll
    for (int n = 0; n < 4; ++n) {
        const float bv = bias[n * 16 + fr];
        accA[n] = f32x4{bv, bv, bv, bv};
        accB[n] = f32x4{bv, bv, bv, bv};
    }

#pragma unroll
    for (int kb = 0; kb < 3; ++kb) {
        const short8 aA = (kb == 0) ? aA0 : (kb == 1) ? aA1 : aA2;
        const short8 aB = (kb == 0) ? aB0 : (kb == 1) ? aB1 : aB2;
#pragma unroll
        for (int nn = 0; nn < 4; ++nn) {
            const short8 bh = *(const short8*)(Wb + (nn * 16 + fr) * 104 + kb * 32 + koff);
            accA[nn] = __builtin_amdgcn_mfma_f32_16x16x32_bf16(aA, bh, accA[nn], 0, 0, 0);
            accB[nn] = __builtin_amdgcn_mfma_f32_16x16x32_bf16(aB, bh, accB[nn], 0, 0, 0);
        }
    }

    // ReLU in place
#pragma unroll
    for (int n = 0; n < 4; ++n)
#pragma unroll
        for (int j = 0; j < 4; ++j) {
            accA[n][j] = fmaxf(accA[n][j], 0.f);
            accB[n][j] = fmaxf(accB[n][j], 0.f);
        }

    // register segment-reduce per tile (lane holds rows rb..rb+3 of col n*16+fr)
#define SEGREDUCE(TT, ACC)                                                    \
    {                                                                         \
        int r = 0;                                                            \
        while (r < 16) {                                                      \
            const int d = ldstw[w][TT][r];                                    \
            int e2 = r + 1;                                                   \
            while (e2 < 16 && ldstw[w][TT][e2] == d) ++e2;                    \
            float v0 = 0.f, v1 = 0.f, v2 = 0.f, v3 = 0.f;                     \
            _Pragma("unroll")                                                 \
            for (int j = 0; j < 4; ++j) {                                     \
                const bool in = (rb + j >= r) && (rb + j < e2);               \
                v0 += in ? ACC[0][j] : 0.f;                                   \
                v1 += in ? ACC[1][j] : 0.f;                                   \
                v2 += in ? ACC[2][j] : 0.f;                                   \
                v3 += in ? ACC[3][j] : 0.f;                                   \
            }                                                                 \
            v0 += __shfl_xor(v0, 16); v0 += __shfl_xor(v0, 32);               \
            v1 += __shfl_xor(v1, 16); v1 += __shfl_xor(v1, 32);               \
            v2 += __shfl_xor(v2, 16); v2 += __shfl_xor(v2, 32);               \
            v3 += __shfl_xor(v3, 16); v3 += __shfl_xor(v3, 32);               \
            const float val = hi4 == 0 ? v0 : hi4 == 1 ? v1 : hi4 == 2 ? v2 : v3; \
            unsafeAtomicAdd(&aggr[(size_t)d * 64 + lane], val);               \
            r = e2;                                                           \
        }                                                                     \
    }
    SEGREDUCE(0, accA)
    SEGREDUCE(1, accB)
#undef SEGREDUCE
}

// ---------------------------------------------------------------------------
// h = xin @ Wr + aggr/max(deg,1); per-block BN partial sums (no atomics).
__global__ __launch_bounds__(256) void k_combine(const float* __restrict__ xin,
                                                 const float* __restrict__ Wr,
                                                 const float* __restrict__ aggr,
                                                 const int*   __restrict__ ihist,
                                                 float* __restrict__ h,
                                                 float* __restrict__ partial) {
    const int lane = threadIdx.x & 63;
    const int wv   = threadIdx.x >> 6;
    const int wid  = (blockIdx.x * blockDim.x + threadIdx.x) >> 6;
    const int nw   = (gridDim.x * blockDim.x) >> 6;

    float w[64];
#pragma unroll
    for (int k = 0; k < 64; ++k) w[k] = Wr[k * 64 + lane];

    float rs = 0.f, rq = 0.f;
    for (int n = wid; n < N_NODES; n += nw) {
        const float* __restrict__ xr = xin + (size_t)n * 64;
        const float c = fmaxf((float)ihist[n], 1.0f);
        float acc = aggr[(size_t)n * 64 + lane] / c;
#pragma unroll
        for (int k = 0; k < 64; ++k) acc += xr[k] * w[k];
        h[(size_t)n * 64 + lane] = acc;
        rs += acc;
        rq += acc * acc;
    }
    __shared__ float ssum[4][64];
    __shared__ float ssq[4][64];
    ssum[wv][lane] = rs;
    ssq[wv][lane]  = rq;
    __syncthreads();
    if (threadIdx.x < 64) {
        float s = ssum[0][lane] + ssum[1][lane] + ssum[2][lane] + ssum[3][lane];
        partial[blockIdx.x * 128 + lane] = s;
    } else if (threadIdx.x < 128) {
        int l = threadIdx.x - 64;
        float q = ssq[0][l] + ssq[1][l] + ssq[2][l] + ssq[3][l];
        partial[blockIdx.x * 128 + 64 + l] = q;
    }
}

// ---------------------------------------------------------------------------
__global__ void k_bnfin(const float* __restrict__ partial, const float* __restrict__ g,
                        const float* __restrict__ be, float* __restrict__ ss) {
    __shared__ float tot[128];
    int t = threadIdx.x;
    float s = 0.f;
    for (int b = 0; b < NB_COMBINE; ++b) s += partial[b * 128 + t];
    tot[t] = s;
    __syncthreads();
    if (t < 64) {
        float mu  = tot[t] * (1.0f / (float)N_NODES);
        float var = tot[64 + t] * (1.0f / (float)N_NODES) - mu * mu;
        float sc  = g[t] * rsqrtf(var + EPS);
        ss[t]      = sc;
        ss[64 + t] = be[t] - mu * sc;
    }
}

// ---------------------------------------------------------------------------
// Fused BN-apply (layer2) + global mean pool partial sums (sorted-run atomics).
__global__ __launch_bounds__(256) void k_bnpool(const float* __restrict__ h,
                                                const float* __restrict__ ss,
                                                const int* __restrict__ batch,
                                                float* __restrict__ gsum) {
    const int lane = threadIdx.x & 63;
    const int wid  = (blockIdx.x * blockDim.x + threadIdx.x) >> 6;
    const int nw   = (gridDim.x * blockDim.x) >> 6;
    const float sc = ss[lane];
    const float sh = ss[64 + lane];
    const int chunk = (N_NODES + nw - 1) / nw;
    const int n0 = wid * chunk;
    const int n1 = min(n0 + chunk, N_NODES);
    int curg = -1;
    float acc = 0.f;
    for (int n = n0; n < n1; ++n) {
        int g = __builtin_amdgcn_readfirstlane(batch[n]);
        if (g != curg) {
            if (curg >= 0) unsafeAtomicAdd(&gsum[curg * 64 + lane], acc);
            curg = g;
            acc = 0.f;
        }
        acc += fmaxf(h[(size_t)n * 64 + lane] * sc + sh, 0.f);
    }
    if (curg >= 0) unsafeAtomicAdd(&gsum[curg * 64 + lane], acc);
}

// ---------------------------------------------------------------------------
__global__ void k_final(const float* __restrict__ gsum, const float* __restrict__ gcnt,
                        const float* __restrict__ Wro, const float* __restrict__ bro,
                        float* __restrict__ out) {
    int g = blockIdx.x;
    int lane = threadIdx.x;
    float v = gsum[g * 64 + lane] / fmaxf(gcnt[g], 1.0f) * Wro[lane];
#pragma unroll
    for (int off = 32; off > 0; off >>= 1) v += __shfl_down(v, off, 64);
    if (lane == 0) out[g] = v + bro[0];
}

// ---------------------------------------------------------------------------
extern "C" void kernel_launch(void* const* d_in, const int* in_sizes, int n_in,
                              void* d_out, int out_size, void* d_ws, size_t ws_size,
                              hipStream_t stream) {
    (void)in_sizes; (void)n_in; (void)out_size; (void)ws_size;
    const float* x    = (const float*)d_in[0];
    const int*   ei   = (const int*)d_in[1];   // [2, E]
    const float* ea   = (const float*)d_in[2];
    const int*   batch= (const int*)d_in[3];
    const float* Wn1  = (const float*)d_in[4];
    const float* bn1  = (const float*)d_in[5];
    const float* Wr1  = (const float*)d_in[6];
    const float* g1   = (const float*)d_in[7];
    const float* be1  = (const float*)d_in[8];
    const float* Wn2  = (const float*)d_in[9];
    const float* bn2  = (const float*)d_in[10];
    const float* Wr2  = (const float*)d_in[11];
    const float* g2   = (const float*)d_in[12];
    const float* be2  = (const float*)d_in[13];
    const float* Wro  = (const float*)d_in[14];
    const float* bro  = (const float*)d_in[15];
    const int* src = ei;
    const int* dst = ei + N_EDGES;

    float* ws = (float*)d_ws;
    // ---- zeroed region: [gsum | aggr | ihist] ----
    float* gsum   = ws;                               // 3200
    float* aggr   = gsum + 3200;                      // N*64
    int*   ihist  = (int*)(aggr + (size_t)N_NODES * 64); // NHPAD
    const size_t zero_floats = 3200 + (size_t)N_NODES * 64 + NHPAD;
    // ---- non-zeroed ----
    float* h      = (float*)(ihist + NHPAD);
    float* hn     = h + (size_t)N_NODES * 64;
    float* gcnt   = hn + (size_t)N_NODES * 64;        // 64
    float* part1  = gcnt + 64;                        // NB*128
    float* part2  = part1 + NB_COMBINE * 128;
    float* ss1    = part2 + NB_COMBINE * 128;         // 128
    float* ss2    = ss1 + 128;                        // 128
    unsigned short* Wb1 = (unsigned short*)(ss2 + 128); // 64*104 ushort each
    unsigned short* Wb2 = Wb1 + 6656;
    int* off     = (int*)(Wb2 + 6656);                // NHPAD
    int* bsum    = off + NHPAD;                       // 128
    int* bscan   = bsum + 128;                        // 128
    int* bcur    = bscan + 128;                       // 128
    int2* epk    = (int2*)(bcur + 128);               // E int2
    int2* binned = epk + N_EDGES;                     // E int2
    unsigned short* xb  = (unsigned short*)(binned + N_EDGES); // N*64
    unsigned short* hb  = xb + (size_t)N_NODES * 64;           // N*64
    unsigned short* eaB = hb + (size_t)N_NODES * 64;           // E*32

    hipMemsetAsync(d_ws, 0, zero_floats * sizeof(float), stream);

    // ---- edge sort by dst: histogram, scan, two-level bin+sort ----
    k_hist<<<512, 256, 0, stream>>>(dst, ihist);
    k_scan1<<<SCAN_B, 512, 0, stream>>>(ihist, off, bsum);
    k_scan2<<<1, 64, 0, stream>>>(bsum, bscan);
    k_scan3<<<SCAN_B, 512, 0, stream>>>(off, bscan);
    k_bcur<<<1, 128, 0, stream>>>(off, bcur);
    k_bin<<<(N_EDGES + BATCH - 1) / BATCH, 256, 0, stream>>>(src, dst, bcur, binned);
    k_sortb<<<NBKT, 256, 0, stream>>>(binned, off, epk);
    k_prepEA<<<N_EDGES * 4 / 256, 256, 0, stream>>>(ea, eaB);

    k_gcnt<<<1, 64, 0, stream>>>(batch, gcnt);
    k_prepW<<<24, 256, 0, stream>>>(Wn1, Wb1);
    k_prepW<<<24, 256, 0, stream>>>(Wn2, Wb2);
    k_prepX<<<(N_NODES * 8 + 255) / 256, 256, 0, stream>>>(x, xb);

    // ---- layer 1 ----
    k_edge<<<N_EDGES / 128, 256, 0, stream>>>(xb, eaB, epk, Wb1, bn1, aggr);
    k_combine<<<NB_COMBINE, 256, 0, stream>>>(x, Wr1, aggr, ihist, h, part1);
    k_bnfin<<<1, 128, 0, stream>>>(part1, g1, be1, ss1);
    k_prepH<<<(N_NODES * 8 + 255) / 256, 256, 0, stream>>>(h, ss1, hn, hb);

    // ---- layer 2 ----
    hipMemsetAsync(aggr, 0, (size_t)N_NODES * 64 * sizeof(float), stream);
    k_edge<<<N_EDGES / 128, 256, 0, stream>>>(hb, eaB, epk, Wb2, bn2, aggr);
    k_combine<<<NB_COMBINE, 256, 0, stream>>>(hn, Wr2, aggr, ihist, h, part2);
    k_bnfin<<<1, 128, 0, stream>>>(part2, g2, be2, ss2);

    // ---- readout (BN-apply fused into pool) ----
    k_bnpool<<<256, 256, 0, stream>>>(h, ss2, batch, gsum);
    k_final<<<NUM_GRAPHS, 64, 0, stream>>>(gsum, gcnt, Wro, bro, (float*)d_out);
}

// Round 13
// 315.373 us; speedup vs baseline: 1.9337x; 1.2037x over previous
//
#include <hip/hip_runtime.h>

#define N_NODES   50000
#define N_EDGES   800000
#define HID       64
#define NUM_GRAPHS 50
#define EPS       1e-5f
#define NWT       3125           // 16-node wave-tiles (3125*16 = 50000)
#define NBC       782            // k_combine blocks = ceil(NWT/4)
#define NHPAD     50176          // 98 * 512, padded histogram/scan size
#define SCAN_B    98
#define NBKT      98             // coarse buckets = dst >> 9 (512 nodes each)
#define BSH       9
#define BATCH     2048           // edges per k_bin block (8 per thread)

typedef __attribute__((ext_vector_type(8))) short short8;
typedef __attribute__((ext_vector_type(4))) float f32x4;

__device__ __forceinline__ unsigned short bfbits(float x) {
    __bf16 h = (__bf16)x;
    return __builtin_bit_cast(unsigned short, h);
}
// 8 fp32 -> 8 bf16 (RTN)
__device__ __forceinline__ short8 cvt8hi(const float4& a, const float4& b) {
    float f[8] = {a.x, a.y, a.z, a.w, b.x, b.y, b.z, b.w};
    short8 hi;
#pragma unroll
    for (int i = 0; i < 8; ++i) hi[i] = (short)bfbits(f[i]);
    return hi;
}

// ---------------------------------------------------------------------------
// Int histogram of dst (degree count).
__global__ __launch_bounds__(256) void k_hist(const int* __restrict__ dst,
                                              int* __restrict__ ihist) {
    int tid = blockIdx.x * blockDim.x + threadIdx.x;
    int stride = gridDim.x * blockDim.x;
    for (int e = tid; e < N_EDGES; e += stride) atomicAdd(&ihist[dst[e]], 1);
}

// Exclusive scan, pass 1: per-block (512 elems) local scan + block sums.
__global__ __launch_bounds__(512) void k_scan1(const int* __restrict__ ihist,
                                               int* __restrict__ off,
                                               int* __restrict__ bsum) {
    __shared__ int s[512];
    const int t = threadIdx.x, i = blockIdx.x * 512 + t;
    const int v = ihist[i];
    s[t] = v;
    __syncthreads();
    for (int o = 1; o < 512; o <<= 1) {
        int u = (t >= o) ? s[t - o] : 0;
        __syncthreads();
        s[t] += u;
        __syncthreads();
    }
    off[i] = s[t] - v;
    if (t == 511) bsum[blockIdx.x] = s[t];
}

// pass 2: serial exclusive scan of the 98 block sums.
__global__ void k_scan2(const int* __restrict__ bsum, int* __restrict__ bscan) {
    if (threadIdx.x == 0) {
        int acc = 0;
        for (int b = 0; b < SCAN_B; ++b) { bscan[b] = acc; acc += bsum[b]; }
    }
}

// pass 3: add block offsets in place.
__global__ __launch_bounds__(512) void k_scan3(int* __restrict__ off,
                                               const int* __restrict__ bscan) {
    const int i = blockIdx.x * 512 + threadIdx.x;
    off[i] += bscan[i >> 9];
}

// bucket cursors = node-scan value at each bucket's first node.
__global__ void k_bcur(const int* __restrict__ off, int* __restrict__ bcur) {
    int b = threadIdx.x;
    if (b < NBKT) bcur[b] = off[b << BSH];
}

// ---------------------------------------------------------------------------
// Pass 1: bin edges into 98 coarse buckets (dst>>9).
__global__ __launch_bounds__(256) void k_bin(const int* __restrict__ src,
                                             const int* __restrict__ dst,
                                             int* __restrict__ bcur,
                                             int2* __restrict__ binned) {
    __shared__ int bh[NBKT], gb[NBKT];
    const int tid = threadIdx.x;
    const int base = blockIdx.x * BATCH + tid * 8;
    int2 rec[8]; int bk[8]; bool val[8];
#pragma unroll
    for (int j = 0; j < 8; ++j) {
        const int e = base + j;
        val[j] = e < N_EDGES;
        if (val[j]) {
            const int d = dst[e];
            rec[j] = int2{src[e] | (d << 16), e};
            bk[j] = d >> BSH;
        } else bk[j] = 0;
    }
    if (tid < NBKT) bh[tid] = 0;
    __syncthreads();
#pragma unroll
    for (int j = 0; j < 8; ++j) if (val[j]) atomicAdd(&bh[bk[j]], 1);
    __syncthreads();
    if (tid < NBKT) { gb[tid] = atomicAdd(&bcur[tid], bh[tid]); bh[tid] = 0; }
    __syncthreads();
#pragma unroll
    for (int j = 0; j < 8; ++j)
        if (val[j]) {
            const int r = atomicAdd(&bh[bk[j]], 1);
            binned[gb[bk[j]] + r] = rec[j];
        }
}

// ---------------------------------------------------------------------------
// Pass 2: one block per bucket; per-node LDS cursors; XCD-local scatter.
__global__ __launch_bounds__(256) void k_sortb(const int2* __restrict__ binned,
                                               const int* __restrict__ off,
                                               int2* __restrict__ epk) {
    __shared__ int cur[512];
    const int b = blockIdx.x;
    const int nbase = b << BSH;
    const int tid = threadIdx.x;
    for (int i = tid; i < 512; i += 256) cur[i] = off[nbase + i];
    const int start = off[nbase];
    const int end = (b == NBKT - 1) ? N_EDGES : off[nbase + 512];
    __syncthreads();
    for (int p = start + tid; p < end; p += 256) {
        const int2 r = binned[p];
        const int d = ((unsigned)r.x) >> 16;
        const int pos = atomicAdd(&cur[d - nbase], 1);
        epk[pos] = r;
    }
}

// ---------------------------------------------------------------------------
// ea[E][32] fp32 -> bf16 [E][32], original order (pure streaming).
__global__ __launch_bounds__(256) void k_prepEA(const float* __restrict__ ea,
                                                unsigned short* __restrict__ eaB) {
    int t = blockIdx.x * blockDim.x + threadIdx.x;
    if (t >= N_EDGES * 4) return;
    float4 a = *(const float4*)(ea + (size_t)t * 8);
    float4 b = *(const float4*)(ea + (size_t)t * 8 + 4);
    *(short8*)(eaB + (size_t)t * 8) = cvt8hi(a, b);
}

// ---------------------------------------------------------------------------
__global__ void k_gcnt(const int* __restrict__ batch, float* __restrict__ gcnt) {
    int g = threadIdx.x;
    if (g >= NUM_GRAPHS) return;
    auto lb = [&](int val) {
        int lo = 0, hi = N_NODES;
        while (lo < hi) { int mid = (lo + hi) >> 1; if (batch[mid] < val) lo = mid + 1; else hi = mid; }
        return lo;
    };
    gcnt[g] = (float)(lb(g + 1) - lb(g));
}

// ---------------------------------------------------------------------------
// Edge-weight prep: W[96][64] fp32 -> Wb [64][104] bf16 (transposed, padded).
__global__ void k_prepW(const float* __restrict__ W, unsigned short* __restrict__ Wb) {
    int t = blockIdx.x * blockDim.x + threadIdx.x;
    if (t >= 96 * 64) return;
    int k = t >> 6, n = t & 63;
    Wb[n * 104 + k] = bfbits(W[t]);
}

// Root-weight prep: Wr[64][64] fp32 -> Wrb [64][64] bf16 transposed.
__global__ void k_prepWr(const float* __restrict__ Wr, unsigned short* __restrict__ Wrb) {
    int t = blockIdx.x * blockDim.x + threadIdx.x;
    if (t >= 64 * 64) return;
    int k = t >> 6, n = t & 63;
    Wrb[n * 64 + k] = bfbits(Wr[t]);
}

// ---------------------------------------------------------------------------
// x[N,64] fp32 -> bf16 [N,64].
__global__ __launch_bounds__(256) void k_prepX(const float* __restrict__ x,
                                               unsigned short* __restrict__ xb) {
    int t = blockIdx.x * blockDim.x + threadIdx.x;
    if (t >= N_NODES * 8) return;
    float4 a = ((const float4*)(x + (size_t)t * 8))[0];
    float4 b = ((const float4*)(x + (size_t)t * 8))[1];
    *(short8*)(xb + (size_t)t * 8) = cvt8hi(a, b);
}

// ---------------------------------------------------------------------------
// BN-apply (layer1) -> bf16 only (fp32 hn is dead; layer-2 consumes hb).
__global__ __launch_bounds__(256) void k_prepH(const float* __restrict__ h,
                                               const float* __restrict__ ss,
                                               unsigned short* __restrict__ hb) {
    int t = blockIdx.x * blockDim.x + threadIdx.x;
    if (t >= N_NODES * 8) return;
    const int f0 = (t & 7) * 8;
    float4 sca = *(const float4*)(ss + f0);
    float4 scb = *(const float4*)(ss + f0 + 4);
    float4 sha = *(const float4*)(ss + 64 + f0);
    float4 shb = *(const float4*)(ss + 64 + f0 + 4);
    const float* r = h + (size_t)t * 8;
    float4 a = ((const float4*)r)[0];
    float4 b = ((const float4*)r)[1];
    a.x = fmaxf(a.x * sca.x + sha.x, 0.f);
    a.y = fmaxf(a.y * sca.y + sha.y, 0.f);
    a.z = fmaxf(a.z * sca.z + sha.z, 0.f);
    a.w = fmaxf(a.w * sca.w + sha.w, 0.f);
    b.x = fmaxf(b.x * scb.x + shb.x, 0.f);
    b.y = fmaxf(b.y * scb.y + shb.y, 0.f);
    b.z = fmaxf(b.z * scb.z + shb.z, 0.f);
    b.w = fmaxf(b.w * scb.w + shb.w, 0.f);
    *(short8*)(hb + (size_t)t * 8) = cvt8hi(a, b);
}

// ---------------------------------------------------------------------------
// Edge message via MFMA, pure bf16 (unchanged from R11).
__global__ __launch_bounds__(256) void k_edge(const unsigned short* __restrict__ xb,
                                              const unsigned short* __restrict__ eaB,
                                              const int2* __restrict__ epk,
                                              const unsigned short* __restrict__ Wb,
                                              const float* __restrict__ bias,
                                              float* __restrict__ aggr) {
    __shared__ int ldstw[4][2][16];

    const int tid  = threadIdx.x;
    const int lane = tid & 63;
    const int w    = tid >> 6;
    const int ew   = (blockIdx.x * 4 + w) * 32;

    const int fr   = lane & 15;
    const int hi4  = lane >> 4;
    const int koff = hi4 * 8;
    const int rb   = hi4 * 4;

    if (lane < 32)
        ldstw[w][lane >> 4][lane & 15] = ((unsigned)epk[ew + lane].x) >> 16;

    const int2 eA = epk[ew + fr];
    const int2 eB = epk[ew + 16 + fr];
    const int sA = eA.x & 0xffff, iA = eA.y;
    const int sB = eB.x & 0xffff, iB = eB.y;

    short8 aA0 = *(const short8*)(xb + (size_t)sA * 64 + koff);
    short8 aA1 = *(const short8*)(xb + (size_t)sA * 64 + 32 + koff);
    short8 aA2 = *(const short8*)(eaB + (size_t)iA * 32 + koff);
    short8 aB0 = *(const short8*)(xb + (size_t)sB * 64 + koff);
    short8 aB1 = *(const short8*)(xb + (size_t)sB * 64 + 32 + koff);
    short8 aB2 = *(const short8*)(eaB + (size_t)iB * 32 + koff);

    f32x4 accA[4], accB[4];
#pragma unroll
    for (int n = 0; n < 4; ++n) {
        const float bv = bias[n * 16 + fr];
        accA[n] = f32x4{bv, bv, bv, bv};
        accB[n] = f32x4{bv, bv, bv, bv};
    }

#pragma unroll
    for (int kb = 0; kb < 3; ++kb) {
        const short8 aA = (kb == 0) ? aA0 : (kb == 1) ? aA1 : aA2;
        const short8 aB = (kb == 0) ? aB0 : (kb == 1) ? aB1 : aB2;
#pragma unroll
        for (int nn = 0; nn < 4; ++nn) {
            const short8 bh = *(const short8*)(Wb + (nn * 16 + fr) * 104 + kb * 32 + koff);
            accA[nn] = __builtin_amdgcn_mfma_f32_16x16x32_bf16(aA, bh, accA[nn], 0, 0, 0);
            accB[nn] = __builtin_amdgcn_mfma_f32_16x16x32_bf16(aB, bh, accB[nn], 0, 0, 0);
        }
    }

#pragma unroll
    for (int n = 0; n < 4; ++n)
#pragma unroll
        for (int j = 0; j < 4; ++j) {
            accA[n][j] = fmaxf(accA[n][j], 0.f);
            accB[n][j] = fmaxf(accB[n][j], 0.f);
        }

#define SEGREDUCE(TT, ACC)                                                    \
    {                                                                         \
        int r = 0;                                                            \
        while (r < 16) {                                                      \
            const int d = ldstw[w][TT][r];                                    \
            int e2 = r + 1;                                                   \
            while (e2 < 16 && ldstw[w][TT][e2] == d) ++e2;                    \
            float v0 = 0.f, v1 = 0.f, v2 = 0.f, v3 = 0.f;                     \
            _Pragma("unroll")                                                 \
            for (int j = 0; j < 4; ++j) {                                     \
                const bool in = (rb + j >= r) && (rb + j < e2);               \
                v0 += in ? ACC[0][j] : 0.f;                                   \
                v1 += in ? ACC[1][j] : 0.f;                                   \
                v2 += in ? ACC[2][j] : 0.f;                                   \
                v3 += in ? ACC[3][j] : 0.f;                                   \
            }                                                                 \
            v0 += __shfl_xor(v0, 16); v0 += __shfl_xor(v0, 32);               \
            v1 += __shfl_xor(v1, 16); v1 += __shfl_xor(v1, 32);               \
            v2 += __shfl_xor(v2, 16); v2 += __shfl_xor(v2, 32);               \
            v3 += __shfl_xor(v3, 16); v3 += __shfl_xor(v3, 32);               \
            const float val = hi4 == 0 ? v0 : hi4 == 1 ? v1 : hi4 == 2 ? v2 : v3; \
            unsafeAtomicAdd(&aggr[(size_t)d * 64 + lane], val);               \
            r = e2;                                                           \
        }                                                                     \
    }
    SEGREDUCE(0, accA)
    SEGREDUCE(1, accB)
#undef SEGREDUCE
}

// ---------------------------------------------------------------------------
// MFMA combine: h = xin_b16 @ Wr + aggr/deg (fp32 accum), BN partials.
// One 16-node tile per wave; A streamed (2 frags), B = Wrb col-tiles; 8 MFMA.
__global__ __launch_bounds__(256) void k_combine(const unsigned short* __restrict__ xbin,
                                                 const unsigned short* __restrict__ Wrb,
                                                 const float* __restrict__ aggr,
                                                 const int*   __restrict__ ihist,
                                                 float* __restrict__ h,
                                                 float* __restrict__ partial) {
    __shared__ float ssum[4][64];
    __shared__ float ssq[4][64];

    const int tid  = threadIdx.x;
    const int lane = tid & 63;
    const int w    = tid >> 6;
    const int wt   = blockIdx.x * 4 + w;     // wave-tile id, < NWT
    const int fr   = lane & 15;
    const int hi4  = lane >> 4;
    const int koff = hi4 * 8;
    const int rb   = hi4 * 4;

    float rs[4] = {0.f, 0.f, 0.f, 0.f};
    float rq[4] = {0.f, 0.f, 0.f, 0.f};

    if (wt < NWT) {
        const int n0 = wt * 16;
        const short8 a0 = *(const short8*)(xbin + (size_t)(n0 + fr) * 64 + koff);
        const short8 a1 = *(const short8*)(xbin + (size_t)(n0 + fr) * 64 + 32 + koff);
        f32x4 acc[4] = {};
#pragma unroll
        for (int kb = 0; kb < 2; ++kb) {
            const short8 a = kb == 0 ? a0 : a1;
#pragma unroll
            for (int nn = 0; nn < 4; ++nn) {
                const short8 bh = *(const short8*)(Wrb + (nn * 16 + fr) * 64 + kb * 32 + koff);
                acc[nn] = __builtin_amdgcn_mfma_f32_16x16x32_bf16(a, bh, acc[nn], 0, 0, 0);
            }
        }
        const int4 degs = *(const int4*)(ihist + n0 + rb);
#pragma unroll
        for (int j = 0; j < 4; ++j) {
            const int dg = (&degs.x)[j];
            const float invc = 1.0f / fmaxf((float)dg, 1.0f);
            const int row = n0 + rb + j;
#pragma unroll
            for (int nn = 0; nn < 4; ++nn) {
                const float v = acc[nn][j] + aggr[(size_t)row * 64 + nn * 16 + fr] * invc;
                h[(size_t)row * 64 + nn * 16 + fr] = v;
                rs[nn] += v;
                rq[nn] += v * v;
            }
        }
    }

#pragma unroll
    for (int nn = 0; nn < 4; ++nn) {
        rs[nn] += __shfl_xor(rs[nn], 16); rs[nn] += __shfl_xor(rs[nn], 32);
        rq[nn] += __shfl_xor(rq[nn], 16); rq[nn] += __shfl_xor(rq[nn], 32);
    }
    if (hi4 == 0) {
#pragma unroll
        for (int nn = 0; nn < 4; ++nn) {
            ssum[w][nn * 16 + fr] = rs[nn];
            ssq[w][nn * 16 + fr]  = rq[nn];
        }
    }
    __syncthreads();
    if (tid < 64) {
        partial[blockIdx.x * 128 + tid] =
            ssum[0][tid] + ssum[1][tid] + ssum[2][tid] + ssum[3][tid];
    } else if (tid < 128) {
        int l = tid - 64;
        partial[blockIdx.x * 128 + 64 + l] =
            ssq[0][l] + ssq[1][l] + ssq[2][l] + ssq[3][l];
    }
}

// ---------------------------------------------------------------------------
__global__ void k_bnfin(const float* __restrict__ partial, const float* __restrict__ g,
                        const float* __restrict__ be, float* __restrict__ ss) {
    __shared__ float tot[128];
    int t = threadIdx.x;
    float s = 0.f;
    for (int b = 0; b < NBC; ++b) s += partial[b * 128 + t];
    tot[t] = s;
    __syncthreads();
    if (t < 64) {
        float mu  = tot[t] * (1.0f / (float)N_NODES);
        float var = tot[64 + t] * (1.0f / (float)N_NODES) - mu * mu;
        float sc  = g[t] * rsqrtf(var + EPS);
        ss[t]      = sc;
        ss[64 + t] = be[t] - mu * sc;
    }
}

// ---------------------------------------------------------------------------
// Fused BN-apply (layer2) + global mean pool partial sums (sorted-run atomics).
__global__ __launch_bounds__(256) void k_bnpool(const float* __restrict__ h,
                                                const float* __restrict__ ss,
                                                const int* __restrict__ batch,
                                                float* __restrict__ gsum) {
    const int lane = threadIdx.x & 63;
    const int wid  = (blockIdx.x * blockDim.x + threadIdx.x) >> 6;
    const int nw   = (gridDim.x * blockDim.x) >> 6;
    const float sc = ss[lane];
    const float sh = ss[64 + lane];
    const int chunk = (N_NODES + nw - 1) / nw;
    const int n0 = wid * chunk;
    const int n1 = min(n0 + chunk, N_NODES);
    int curg = -1;
    float acc = 0.f;
    for (int n = n0; n < n1; ++n) {
        int g = __builtin_amdgcn_readfirstlane(batch[n]);
        if (g != curg) {
            if (curg >= 0) unsafeAtomicAdd(&gsum[curg * 64 + lane], acc);
            curg = g;
            acc = 0.f;
        }
        acc += fmaxf(h[(size_t)n * 64 + lane] * sc + sh, 0.f);
    }
    if (curg >= 0) unsafeAtomicAdd(&gsum[curg * 64 + lane], acc);
}

// ---------------------------------------------------------------------------
__global__ void k_final(const float* __restrict__ gsum, const float* __restrict__ gcnt,
                        const float* __restrict__ Wro, const float* __restrict__ bro,
                        float* __restrict__ out) {
    int g = blockIdx.x;
    int lane = threadIdx.x;
    float v = gsum[g * 64 + lane] / fmaxf(gcnt[g], 1.0f) * Wro[lane];
#pragma unroll
    for (int off = 32; off > 0; off >>= 1) v += __shfl_down(v, off, 64);
    if (lane == 0) out[g] = v + bro[0];
}

// ---------------------------------------------------------------------------
extern "C" void kernel_launch(void* const* d_in, const int* in_sizes, int n_in,
                              void* d_out, int out_size, void* d_ws, size_t ws_size,
                              hipStream_t stream) {
    (void)in_sizes; (void)n_in; (void)out_size; (void)ws_size;
    const float* x    = (const float*)d_in[0];
    const int*   ei   = (const int*)d_in[1];   // [2, E]
    const float* ea   = (const float*)d_in[2];
    const int*   batch= (const int*)d_in[3];
    const float* Wn1  = (const float*)d_in[4];
    const float* bn1  = (const float*)d_in[5];
    const float* Wr1  = (const float*)d_in[6];
    const float* g1   = (const float*)d_in[7];
    const float* be1  = (const float*)d_in[8];
    const float* Wn2  = (const float*)d_in[9];
    const float* bn2  = (const float*)d_in[10];
    const float* Wr2  = (const float*)d_in[11];
    const float* g2   = (const float*)d_in[12];
    const float* be2  = (const float*)d_in[13];
    const float* Wro  = (const float*)d_in[14];
    const float* bro  = (const float*)d_in[15];
    const int* src = ei;
    const int* dst = ei + N_EDGES;

    float* ws = (float*)d_ws;
    // ---- zeroed region: [gsum | aggr | ihist] ----
    float* gsum   = ws;                               // 3200
    float* aggr   = gsum + 3200;                      // N*64
    int*   ihist  = (int*)(aggr + (size_t)N_NODES * 64); // NHPAD
    const size_t zero_floats = 3200 + (size_t)N_NODES * 64 + NHPAD;
    // ---- non-zeroed ----
    float* h      = (float*)(ihist + NHPAD);          // N*64
    float* gcnt   = h + (size_t)N_NODES * 64;         // 64
    float* part1  = gcnt + 64;                        // NBC*128
    float* part2  = part1 + NBC * 128;                // NBC*128
    float* ss1    = part2 + NBC * 128;                // 128
    float* ss2    = ss1 + 128;                        // 128
    unsigned short* Wb1  = (unsigned short*)(ss2 + 128); // 64*104
    unsigned short* Wb2  = Wb1 + 6656;
    unsigned short* Wrb1 = Wb2 + 6656;                // 64*64
    unsigned short* Wrb2 = Wrb1 + 4096;
    int* off     = (int*)(Wrb2 + 4096);               // NHPAD
    int* bsum    = off + NHPAD;                       // 128
    int* bscan   = bsum + 128;                        // 128
    int* bcur    = bscan + 128;                       // 128
    int2* epk    = (int2*)(bcur + 128);               // E int2
    int2* binned = epk + N_EDGES;                     // E int2
    unsigned short* xb  = (unsigned short*)(binned + N_EDGES); // N*64
    unsigned short* hb  = xb + (size_t)N_NODES * 64;           // N*64
    unsigned short* eaB = hb + (size_t)N_NODES * 64;           // E*32

    hipMemsetAsync(d_ws, 0, zero_floats * sizeof(float), stream);

    // ---- edge sort by dst: histogram, scan, two-level bin+sort ----
    k_hist<<<512, 256, 0, stream>>>(dst, ihist);
    k_scan1<<<SCAN_B, 512, 0, stream>>>(ihist, off, bsum);
    k_scan2<<<1, 64, 0, stream>>>(bsum, bscan);
    k_scan3<<<SCAN_B, 512, 0, stream>>>(off, bscan);
    k_bcur<<<1, 128, 0, stream>>>(off, bcur);
    k_bin<<<(N_EDGES + BATCH - 1) / BATCH, 256, 0, stream>>>(src, dst, bcur, binned);
    k_sortb<<<NBKT, 256, 0, stream>>>(binned, off, epk);
    k_prepEA<<<N_EDGES * 4 / 256, 256, 0, stream>>>(ea, eaB);

    k_gcnt<<<1, 64, 0, stream>>>(batch, gcnt);
    k_prepW<<<24, 256, 0, stream>>>(Wn1, Wb1);
    k_prepW<<<24, 256, 0, stream>>>(Wn2, Wb2);
    k_prepWr<<<16, 256, 0, stream>>>(Wr1, Wrb1);
    k_prepWr<<<16, 256, 0, stream>>>(Wr2, Wrb2);
    k_prepX<<<(N_NODES * 8 + 255) / 256, 256, 0, stream>>>(x, xb);

    // ---- layer 1 ----
    k_edge<<<N_EDGES / 128, 256, 0, stream>>>(xb, eaB, epk, Wb1, bn1, aggr);
    k_combine<<<NBC, 256, 0, stream>>>(xb, Wrb1, aggr, ihist, h, part1);
    k_bnfin<<<1, 128, 0, stream>>>(part1, g1, be1, ss1);
    k_prepH<<<(N_NODES * 8 + 255) / 256, 256, 0, stream>>>(h, ss1, hb);

    // ---- layer 2 ----
    hipMemsetAsync(aggr, 0, (size_t)N_NODES * 64 * sizeof(float), stream);
    k_edge<<<N_EDGES / 128, 256, 0, stream>>>(hb, eaB, epk, Wb2, bn2, aggr);
    k_combine<<<NBC, 256, 0, stream>>>(hb, Wrb2, aggr, ihist, h, part2);
    k_bnfin<<<1, 128, 0, stream>>>(part2, g2, be2, ss2);

    // ---- readout (BN-apply fused into pool) ----
    k_bnpool<<<256, 256, 0, stream>>>(h, ss2, batch, gsum);
    k_final<<<NUM_GRAPHS, 64, 0, stream>>>(gsum, gcnt, Wro, bro, (float*)d_out);
}